// Round 8
// baseline (217.507 us; speedup 1.0000x reference)
//
#include <hip/hip_runtime.h>

#define DI __device__ __forceinline__

typedef __attribute__((ext_vector_type(8))) short s16x8;
typedef __attribute__((ext_vector_type(4))) short s16x4;
typedef __attribute__((ext_vector_type(4))) float f32x4;

DI unsigned short f2bf(float f){
  unsigned u = __float_as_uint(f);
  u = (u + 0x7FFFu + ((u >> 16) & 1u)) >> 16;
  return (unsigned short)u;
}
DI float bf2f(unsigned short h){
  return __uint_as_float(((unsigned)h) << 16);
}
DI float exp2i(float x){ float r; asm("v_exp_f32 %0, %1" : "=v"(r) : "v"(x)); return r; }

DI void gll16(const void* g, void* l){
  __builtin_amdgcn_global_load_lds((const __attribute__((address_space(1))) void*)g,
                                   (__attribute__((address_space(3))) void*)l, 16, 0, 0);
}

#define VMCNT(n) asm volatile("s_waitcnt vmcnt(" #n ")" ::: "memory")

// ---------------- elementwise fp32 -> bf16 ----------------
__global__ void cvt_kernel(const float* __restrict__ in, unsigned short* __restrict__ out, int n8){
  int i = blockIdx.x * blockDim.x + threadIdx.x;
  if (i >= n8) return;
  const float4* p = (const float4*)in + (size_t)i * 2;
  float4 a = p[0], b = p[1];
  s16x8 o;
  o[0] = (short)f2bf(a.x); o[1] = (short)f2bf(a.y); o[2] = (short)f2bf(a.z); o[3] = (short)f2bf(a.w);
  o[4] = (short)f2bf(b.x); o[5] = (short)f2bf(b.y); o[6] = (short)f2bf(b.z); o[7] = (short)f2bf(b.w);
  ((s16x8*)out)[i] = o;
}

// ---------------- transpose + convert: in fp32 [R][C] -> out bf16 [C][R] ----------------
__global__ void transpose_cvt(const float* __restrict__ in, unsigned short* __restrict__ out, int R, int C){
  __shared__ float t[32][33];
  int c0 = blockIdx.x * 32, r0 = blockIdx.y * 32;
  int tx = threadIdx.x, ty = threadIdx.y; // 32 x 8
  #pragma unroll
  for (int i = 0; i < 4; i++)
    t[ty + i*8][tx] = in[(size_t)(r0 + ty + i*8) * C + c0 + tx];
  __syncthreads();
  #pragma unroll
  for (int i = 0; i < 4; i++)
    out[(size_t)(c0 + ty + i*8) * R + r0 + tx] = f2bf(t[tx][ty + i*8]);
}

// ---------------- GEMM (m97 structure): C[M x N] = A[M x K] * Wt[N x K]^T + bias ----------------
// MODE 0 (BM=128): qkv -> qbuf rows (Q pre-scaled by log2e), ktile swz, vtile swz.
// MODE 1 (BM=64): proj -> fp32 out.
template<int MODE, int BM>
__launch_bounds__(256)
__global__ void gemm_kernel(const unsigned short* __restrict__ A,
                            const unsigned short* __restrict__ Wt,
                            const float* __restrict__ bias,
                            int N,
                            unsigned short* __restrict__ qb,
                            unsigned short* __restrict__ kb,
                            unsigned short* __restrict__ vt,
                            float* __restrict__ out)
{
  constexpr int MI = BM / 32;
  constexpr int AC = BM / 32;
  const int K = 1024;
  __shared__ unsigned short As[BM * 64];
  __shared__ unsigned short Bs[128 * 64];
  int m0 = blockIdx.y * BM, n0 = blockIdx.x * 128;
  int tid = threadIdx.x;
  int lane = tid & 63, w = tid >> 6;
  int row_l = lane & 15, kgrp = lane >> 4;
  int wm = (w >> 1) * (MI * 16), wn = (w & 1) * 64;

  const unsigned short* asrc[AC];
  const unsigned short* bsrc[4];
  int ldsoA[AC], ldsoB[4];
  int chunk = (lane & 7) ^ (lane >> 3);
  #pragma unroll
  for (int c4 = 0; c4 < AC; c4++){
    int r = c4*32 + w*8 + (lane >> 3);
    asrc[c4] = A + (size_t)(m0 + r) * K + chunk*8;
    ldsoA[c4] = (c4*32 + w*8) * 64;
  }
  #pragma unroll
  for (int c4 = 0; c4 < 4; c4++){
    int r = c4*32 + w*8 + (lane >> 3);
    bsrc[c4] = Wt + (size_t)(n0 + r) * K + chunk*8;
    ldsoB[c4] = (c4*32 + w*8) * 64;
  }
  int eA[MI], eB[4];
  #pragma unroll
  for (int i = 0; i < MI; i++){
    int ra = wm + i*16 + row_l;
    eA[i] = (ra*64 + kgrp*8) ^ ((ra & 7) << 3);
  }
  #pragma unroll
  for (int i = 0; i < 4; i++){
    int rb = wn + i*16 + row_l;
    eB[i] = (rb*64 + kgrp*8) ^ ((rb & 7) << 3);
  }

  f32x4 acc[MI][4];
  #pragma unroll
  for (int i = 0; i < MI; i++)
    #pragma unroll
    for (int j = 0; j < 4; j++)
      acc[i][j] = (f32x4){0.f, 0.f, 0.f, 0.f};

  for (int k0 = 0; k0 < K; k0 += 64){
    #pragma unroll
    for (int c4 = 0; c4 < AC; c4++)
      gll16(asrc[c4] + k0, (void*)(As + ldsoA[c4]));
    #pragma unroll
    for (int c4 = 0; c4 < 4; c4++)
      gll16(bsrc[c4] + k0, (void*)(Bs + ldsoB[c4]));
    __syncthreads();
    #pragma unroll
    for (int kc = 0; kc < 2; kc++){
      s16x8 af[MI], bfr[4];
      #pragma unroll
      for (int mi = 0; mi < MI; mi++)
        af[mi] = *(const s16x8*)&As[eA[mi] ^ (kc*32)];
      #pragma unroll
      for (int ni = 0; ni < 4; ni++)
        bfr[ni] = *(const s16x8*)&Bs[eB[ni] ^ (kc*32)];
      #pragma unroll
      for (int mi = 0; mi < MI; mi++)
        #pragma unroll
        for (int ni = 0; ni < 4; ni++)
          acc[mi][ni] = __builtin_amdgcn_mfma_f32_16x16x32_bf16(af[mi], bfr[ni], acc[mi][ni], 0, 0, 0);
    }
    __syncthreads();
  }

  #pragma unroll
  for (int mi = 0; mi < MI; mi++){
    #pragma unroll
    for (int ni = 0; ni < 4; ni++){
      #pragma unroll
      for (int j = 0; j < 4; j++){
        int gr = m0 + wm + mi*16 + kgrp*4 + j;
        int gc = n0 + wn + ni*16 + row_l;
        float v = acc[mi][ni][j] + bias[gc];
        if (MODE == 0){
          int h = gc / 192, cc = gc % 192;
          int b = gr >> 11, s = gr & 2047;
          if (cc < 64){
            // Q pre-scaled by log2(e): downstream uses raw v_exp_f32 (exp2)
            qb[(size_t)gr * 1024 + h*64 + cc] = f2bf(v * 1.44269504f);
          } else if (cc < 128){
            int d = cc - 64; int kt = s >> 6, kk = s & 63;
            kb[(size_t)((b*16 + h)*32 + kt) * 4096 + ((kk*64 + d) ^ ((kk & 7) << 3))] = f2bf(v);
          } else {
            int d = cc - 128; int kt = s >> 6, kk = s & 63;
            vt[(size_t)((b*16 + h)*32 + kt) * 4096 + ((d*64 + kk) ^ ((d & 7) << 3))] = f2bf(v);
          }
        } else {
          out[(size_t)gr * N + gc] = v;
        }
      }
    }
  }
}

// ---------------- V suffix sums (64-key granularity): sufv[bh][t in 0..32][64d] ----------------
__global__ void sufv_kernel(const unsigned short* __restrict__ vt, float* __restrict__ sufv){
  __shared__ float tot[4][64];
  int bh = blockIdx.x;                 // 32
  int tid = threadIdx.x;               // 256
  int tq = tid >> 6, d = tid & 63;
  const unsigned short* base = vt + (size_t)bh * 32 * 4096;
  float s[8];
  float run = 0.f;
  for (int j = 7; j >= 0; j--){
    int t = tq*8 + j;
    float rs = 0.f;
    #pragma unroll
    for (int c = 0; c < 8; c++){
      int idx = (d*64 + c*8) ^ ((d & 7) << 3);
      s16x8 v = *(const s16x8*)&base[(size_t)t*4096 + idx];
      #pragma unroll
      for (int e = 0; e < 8; e++) rs += bf2f((unsigned short)v[e]);
    }
    run += rs; s[j] = run;
  }
  tot[tq][d] = run;
  __syncthreads();
  float carry = 0.f;
  for (int t2 = tq+1; t2 < 4; t2++) carry += tot[t2][d];
  #pragma unroll
  for (int j = 0; j < 8; j++)
    sufv[((size_t)bh*33 + tq*8 + j)*64 + d] = s[j] + carry;
  if (tid < 64) sufv[((size_t)bh*33 + 32)*64 + tid] = 0.f;
}

// ---------------- D-pass: invb[b][q][k] (bf16) = 1 / sum_h exp(s_h(q,k)) over causal triangle ----------------
// kt-major tile enumeration + XCD swizzle; 4-buffer 2-deep LDS ring. Q pre-scaled -> raw exp2.
__launch_bounds__(256)
__global__ void dpass_kernel(const unsigned short* __restrict__ qbuf,
                             const unsigned short* __restrict__ kb,
                             unsigned short* __restrict__ invb)
{
  __shared__ unsigned short Kst[4][4096];
  int bid = blockIdx.x;                       // 1056 = 8 * 132
  int blk = (bid & 7) * 132 + (bid >> 3);     // XCD swizzle (bijective)
  int b = blk / 528, t = blk % 528;
  int kt = (int)(32.5f - sqrtf(1056.25f - 2.f*t));
  while (kt*(65-kt)/2 > t) kt--;
  while ((kt+1)*(64-kt)/2 <= t) kt++;
  int qt = kt + (t - kt*(65-kt)/2);

  int tid = threadIdx.x, lane = tid & 63, w = tid >> 6;
  int row_l = lane & 15, kgrp = lane >> 4;

  const unsigned short* ktb = kb + ((size_t)(b*16)*32 + kt) * 4096;
  int sgoff = (w*128 + lane)*8;

  auto stage = [&](int hh, int buf){
    const unsigned short* src = ktb + (size_t)hh * 131072;
    gll16(src + sgoff,       (void*)(&Kst[buf][0] + w*1024));
    gll16(src + sgoff + 512, (void*)(&Kst[buf][0] + w*1024 + 512));
  };

  int e0[4];
  #pragma unroll
  for (int ks = 0; ks < 4; ks++){
    int row = ks*16 + row_l;
    e0[ks] = (row*64 + kgrp*8) ^ ((row & 7) << 3);
  }

  stage(0, 0);
  stage(1, 1);

  f32x4 esum[4];
  #pragma unroll
  for (int ks = 0; ks < 4; ks++) esum[ks] = (f32x4){0.f,0.f,0.f,0.f};

  const unsigned short* qrow_p = qbuf + (size_t)(b*2048 + qt*64 + w*16 + row_l) * 1024;
  s16x8 qf0 = *(const s16x8*)&qrow_p[kgrp*8];
  s16x8 qf1 = *(const s16x8*)&qrow_p[32 + kgrp*8];

  for (int h = 0; h < 16; h++){
    s16x8 qn0, qn1;
    if (h < 15){
      qn0 = *(const s16x8*)&qrow_p[(h+1)*64 + kgrp*8];
      qn1 = *(const s16x8*)&qrow_p[(h+1)*64 + 32 + kgrp*8];
    }
    if (h + 2 < 16) stage(h+2, (h+2) & 3);
    __builtin_amdgcn_sched_barrier(0);
    if (h < 14)      VMCNT(8);
    else if (h < 15) VMCNT(6);
    else             VMCNT(2);
    __builtin_amdgcn_sched_barrier(0);
    __builtin_amdgcn_s_barrier();
    __builtin_amdgcn_sched_barrier(0);

    const unsigned short* kl = &Kst[h & 3][0];
    #pragma unroll
    for (int ks = 0; ks < 4; ks++){
      s16x8 a0 = *(const s16x8*)&kl[e0[ks]];
      s16x8 a1 = *(const s16x8*)&kl[e0[ks] ^ 32];
      f32x4 sc = __builtin_amdgcn_mfma_f32_16x16x32_bf16(a0, qf0, (f32x4){0.f,0.f,0.f,0.f}, 0, 0, 0);
      sc = __builtin_amdgcn_mfma_f32_16x16x32_bf16(a1, qf1, sc, 0, 0, 0);
      #pragma unroll
      for (int j = 0; j < 4; j++) esum[ks][j] += exp2i(sc[j]);
    }
    if (h < 15){ qf0 = qn0; qf1 = qn1; }
  }

  int qcol = qt*64 + w*16 + row_l;
  unsigned short* dst = invb + (size_t)b*4194304 + (size_t)qcol*2048 + kt*64 + kgrp*4;
  #pragma unroll
  for (int ks = 0; ks < 4; ks++){
    float r0 = 1.f/esum[ks][0], r1 = 1.f/esum[ks][1];
    float r2 = 1.f/esum[ks][2], r3 = 1.f/esum[ks][3];
    unsigned lo, hi;
    asm("v_cvt_pk_bf16_f32 %0, %1, %2" : "=v"(lo) : "v"(r0), "v"(r1));
    asm("v_cvt_pk_bf16_f32 %0, %1, %2" : "=v"(hi) : "v"(r2), "v"(r3));
    uint2 pk; pk.x = lo; pk.y = hi;
    *(uint2*)&dst[ks*16] = pk;
  }
}

// ---------------- PV-pass v4: barrier-free single-wave jobs, double-buffered K/V registers ----------------
// grid 4096 = (b, h, pair i, half, w) XCD-swizzled; 64 threads; no staging LDS (2.3 KB Ws only).
// __launch_bounds__(64, 2): <=256 VGPR, ~2 waves/SIMD, 8 independent streams/CU.
// Tile kt+1's 16 K/V loads issue before tile kt's compute (~600 cyc lead); compiler counted-waits.

#define PV_STEP(KC, VC, KN, VN) {                                               \
  bool nx1 = (kt + 1 < k1t);                                                    \
  if (nx1){                                                                     \
    const unsigned short* kn_ = KT + (size_t)(kt+1)*4096;                       \
    const unsigned short* vn_ = VT + (size_t)(kt+1)*4096;                       \
    _Pragma("unroll") for (int ks = 0; ks < 4; ks++){                           \
      KN[2*ks]   = *(const s16x8*)&kn_[eK[ks]];                                 \
      KN[2*ks+1] = *(const s16x8*)&kn_[eK[ks] ^ 32];                            \
    }                                                                           \
    _Pragma("unroll") for (int kc = 0; kc < 2; kc++)                            \
      _Pragma("unroll") for (int dq = 0; dq < 4; dq++)                          \
        VN[kc*4+dq] = *(const s16x8*)&vn_[eK[dq] ^ (kc*32)];                    \
  }                                                                             \
  s16x4 icur[4];                                                                \
  _Pragma("unroll") for (int ks = 0; ks < 4; ks++) icur[ks] = i1[ks];           \
  if (nx1){                                                                     \
    _Pragma("unroll") for (int ks = 0; ks < 4; ks++)                            \
      i1[ks] = *(const s16x4*)&ivrow[(kt+1)*64 + ks*16];                        \
  }                                                                             \
  f32x4 sc[4];                                                                  \
  __builtin_amdgcn_s_setprio(1);                                                \
  _Pragma("unroll") for (int ks = 0; ks < 4; ks++){                             \
    sc[ks] = __builtin_amdgcn_mfma_f32_16x16x32_bf16(KC[2*ks], qf0, (f32x4){0.f,0.f,0.f,0.f}, 0, 0, 0); \
    sc[ks] = __builtin_amdgcn_mfma_f32_16x16x32_bf16(KC[2*ks+1], qf1, sc[ks], 0, 0, 0); \
  }                                                                             \
  __builtin_amdgcn_s_setprio(0);                                                \
  if (kt == qt){                                                                \
    int kbase = kt*64 + kgrp*4;                                                 \
    _Pragma("unroll") for (int ks = 0; ks < 4; ks++){                           \
      _Pragma("unroll") for (int j = 0; j < 4; j++){                            \
        float wv = exp2i(sc[ks][j]) * bf2f((unsigned short)icur[ks][j]);        \
        sc[ks][j] = (kbase + ks*16 + j > qv) ? 0.0625f : wv;                    \
      }                                                                         \
      unsigned lo, hi;                                                          \
      asm("v_cvt_pk_bf16_f32 %0, %1, %2" : "=v"(lo) : "v"(sc[ks][0]), "v"(sc[ks][1])); \
      asm("v_cvt_pk_bf16_f32 %0, %1, %2" : "=v"(hi) : "v"(sc[ks][2]), "v"(sc[ks][3])); \
      uint2 pk2; pk2.x = lo; pk2.y = hi;                                        \
      *(uint2*)&Wsh[row_l*72 + ks*16 + kgrp*4] = pk2;                           \
    }                                                                           \
  } else {                                                                      \
    _Pragma("unroll") for (int ks = 0; ks < 4; ks++){                           \
      _Pragma("unroll") for (int j = 0; j < 4; j++)                             \
        sc[ks][j] = exp2i(sc[ks][j]) * bf2f((unsigned short)icur[ks][j]);       \
      unsigned lo, hi;                                                          \
      asm("v_cvt_pk_bf16_f32 %0, %1, %2" : "=v"(lo) : "v"(sc[ks][0]), "v"(sc[ks][1])); \
      asm("v_cvt_pk_bf16_f32 %0, %1, %2" : "=v"(hi) : "v"(sc[ks][2]), "v"(sc[ks][3])); \
      uint2 pk2; pk2.x = lo; pk2.y = hi;                                        \
      *(uint2*)&Wsh[row_l*72 + ks*16 + kgrp*4] = pk2;                           \
    }                                                                           \
  }                                                                             \
  __builtin_amdgcn_s_setprio(1);                                                \
  _Pragma("unroll") for (int kc = 0; kc < 2; kc++){                             \
    s16x8 af = *(const s16x8*)&Wsh[row_l*72 + kc*32 + kgrp*8];                  \
    _Pragma("unroll") for (int dq = 0; dq < 4; dq++)                            \
      pvv[dq] = __builtin_amdgcn_mfma_f32_16x16x32_bf16(af, VC[kc*4+dq], pvv[dq], 0, 0, 0); \
  }                                                                             \
  __builtin_amdgcn_s_setprio(0);                                                \
}

__launch_bounds__(64, 2)
__global__ void pv_kernel(const unsigned short* __restrict__ qbuf,
                          const unsigned short* __restrict__ kb,
                          const unsigned short* __restrict__ vt,
                          const unsigned short* __restrict__ invb,
                          const float* __restrict__ sufv,
                          unsigned short* __restrict__ ab,
                          float* __restrict__ pb)
{
  __shared__ unsigned short Wsh[16 * 72];

  int bid = blockIdx.x;                              // 4096 = 8 * 512
  int blk = ((bid & 7) << 9) | (bid >> 3);           // XCD swizzle: XCD x gets contiguous 512-run
  int w    = blk & 3;
  int half = (blk >> 2) & 1;
  int i    = (blk >> 3) & 15;
  int h    = (blk >> 7) & 15;
  int b    = blk >> 11;
  int qsm = i, qbig = 31 - i;

  int lane = threadIdx.x & 63;
  int row_l = lane & 15, kgrp = lane >> 4;

  const unsigned short* KT = kb + (size_t)((b*16 + h)*32) * 4096;
  const unsigned short* VT = vt + (size_t)((b*16 + h)*32) * 4096;

  int eK[4];
  #pragma unroll
  for (int ks = 0; ks < 4; ks++)
    eK[ks] = ((ks*16 + row_l)*64 + kgrp*8) ^ ((row_l & 7) << 3);

  auto run = [&](int qt, int k0t, int k1t, int mode){
    int q0 = qt * 64;
    int qv = q0 + w*16 + row_l;
    const unsigned short* qrow_p = qbuf + (size_t)(b*2048 + qv) * 1024 + h*64;
    s16x8 qf0 = *(const s16x8*)&qrow_p[kgrp*8];
    s16x8 qf1 = *(const s16x8*)&qrow_p[32 + kgrp*8];
    const unsigned short* ivrow = invb + (size_t)b*4194304 + (size_t)qv*2048 + kgrp*4;

    f32x4 pvv[4];
    #pragma unroll
    for (int d = 0; d < 4; d++) pvv[d] = (f32x4){0.f,0.f,0.f,0.f};

    // prologue: tile k0t into A buffers, invD(k0t) into i1
    s16x8 kA[8], kB[8], vA[8], vB[8];
    s16x4 i1[4];
    {
      const unsigned short* kp = KT + (size_t)k0t*4096;
      const unsigned short* vp = VT + (size_t)k0t*4096;
      #pragma unroll
      for (int ks = 0; ks < 4; ks++){
        kA[2*ks]   = *(const s16x8*)&kp[eK[ks]];
        kA[2*ks+1] = *(const s16x8*)&kp[eK[ks] ^ 32];
      }
      #pragma unroll
      for (int kc = 0; kc < 2; kc++)
        #pragma unroll
        for (int dq = 0; dq < 4; dq++)
          vA[kc*4+dq] = *(const s16x8*)&vp[eK[dq] ^ (kc*32)];
      #pragma unroll
      for (int ks = 0; ks < 4; ks++)
        i1[ks] = *(const s16x4*)&ivrow[k0t*64 + ks*16];
    }

    int kt = k0t;
    while (true){
      PV_STEP(kA, vA, kB, vB);
      if (++kt == k1t) break;
      PV_STEP(kB, vB, kA, vA);
      if (++kt == k1t) break;
    }

    // epilogue: out rows q = q0 + w*16 + kgrp*4 + j; cols d = dq*16 + row_l
    if (mode == 0){
      int tsuf = qt + 1;
      #pragma unroll
      for (int dq = 0; dq < 4; dq++){
        int d = dq*16 + row_l;
        float suf = sufv[((size_t)(b*16 + h)*33 + tsuf)*64 + d];
        #pragma unroll
        for (int j = 0; j < 4; j++){
          int qo = q0 + w*16 + kgrp*4 + j;
          ab[(size_t)(b*2048 + qo)*1024 + h*64 + d] = f2bf(pvv[dq][j] + 0.0625f * suf);
        }
      }
    } else {
      float* pr = pb + ((size_t)((b*16 + h)*16 + i)*2 + (mode - 1)) * 4096;
      #pragma unroll
      for (int dq = 0; dq < 4; dq++){
        int d = dq*16 + row_l;
        #pragma unroll
        for (int j = 0; j < 4; j++)
          pr[(w*16 + kgrp*4 + j)*64 + d] = pvv[dq][j];
      }
    }
  };

  if (half == 0){
    run(qsm, 0, i + 1, 0);
    run(qbig, 0, 16 - i, 1);
  } else {
    run(qbig, 16 - i, 32 - i, 2);
  }
}

// ---------------- reduce split partials + suffix tail -> abuf ----------------
__global__ void reduce_kernel(const float* __restrict__ pb,
                              const float* __restrict__ sufv,
                              unsigned short* __restrict__ ab)
{
  int blk = blockIdx.x;               // 512 = (b,h,i)
  int b = blk >> 8, rr = blk & 255;
  int h = rr >> 4, i = rr & 15;
  int qbig = 31 - i, tsuf = 32 - i;
  int t = threadIdx.x;
  int q = t >> 2, dbase = (t & 3) * 16;
  const float* p0 = pb + ((size_t)((b*16 + h)*16 + i)*2 + 0)*4096 + q*64 + dbase;
  const float* p1 = p0 + 4096;
  const float* sf = sufv + ((size_t)(b*16 + h)*33 + tsuf)*64 + dbase;
  unsigned short* op = ab + (size_t)(b*2048 + qbig*64 + q)*1024 + h*64 + dbase;
  #pragma unroll
  for (int e = 0; e < 4; e++){
    float4 a = *(const float4*)(p0 + e*4);
    float4 bb = *(const float4*)(p1 + e*4);
    float4 s = *(const float4*)(sf + e*4);
    unsigned short o[4];
    o[0] = f2bf(a.x + bb.x + 0.0625f * s.x);
    o[1] = f2bf(a.y + bb.y + 0.0625f * s.y);
    o[2] = f2bf(a.z + bb.z + 0.0625f * s.z);
    o[3] = f2bf(a.w + bb.w + 0.0625f * s.w);
    *(s16x4*)(op + e*4) = *(s16x4*)o;
  }
}

// ---------------- host ----------------
extern "C" void kernel_launch(void* const* d_in, const int* in_sizes, int n_in,
                              void* d_out, int out_size, void* d_ws, size_t ws_size,
                              hipStream_t stream) {
  (void)in_sizes; (void)n_in; (void)out_size; (void)ws_size;
  const float* x  = (const float*)d_in[0];
  const float* Wa = (const float*)d_in[1];
  const float* ba = (const float*)d_in[2];
  const float* Wp = (const float*)d_in[3];
  const float* bp = (const float*)d_in[4];
  float* out = (float*)d_out;

  char* ws = (char*)d_ws;
  size_t off = 0;
  auto alloc = [&](size_t bytes) -> void* {
    void* p = ws + off;
    off += (bytes + 255) & ~(size_t)255;
    return p;
  };
  // region A (16 MB): xb (8 MB) + WaT (6 MB) alias pbuf — both dead before pv_kernel writes partials
  float* pbuf          = (float*)alloc((size_t)16*1024*1024);
  unsigned short* xb   = (unsigned short*)((char*)pbuf);
  unsigned short* WaT  = (unsigned short*)((char*)pbuf + (size_t)4096*1024*2);
  unsigned short* WpT  = (unsigned short*)alloc((size_t)1024*1024*2);
  unsigned short* qbuf = (unsigned short*)alloc((size_t)4096*1024*2);
  unsigned short* ktile= (unsigned short*)alloc((size_t)4096*1024*2);
  unsigned short* vtile= (unsigned short*)alloc((size_t)4096*1024*2);
  unsigned short* abuf = (unsigned short*)alloc((size_t)4096*1024*2);
  unsigned short* invb = (unsigned short*)alloc((size_t)2*2048*2048*2); // bf16 invD
  float* sufv          = (float*)alloc((size_t)32*33*64*4);

  // 1) conversions
  cvt_kernel<<<2048, 256, 0, stream>>>(x, xb, 4096*1024/8);
  transpose_cvt<<<dim3(3072/32, 1024/32), dim3(32, 8), 0, stream>>>(Wa, WaT, 1024, 3072);
  transpose_cvt<<<dim3(1024/32, 1024/32), dim3(32, 8), 0, stream>>>(Wp, WpT, 1024, 1024);

  // 2) QKV GEMM -> qbuf / ktile / vtile
  gemm_kernel<0,128><<<dim3(24, 32), 256, 0, stream>>>(xb, WaT, ba, 3072, qbuf, ktile, vtile, nullptr);

  // 3) V suffix sums
  sufv_kernel<<<32, 256, 0, stream>>>(vtile, sufv);

  // 4) denominator pass (bf16 invD)
  dpass_kernel<<<1056, 256, 0, stream>>>(qbuf, ktile, invb);

  // 5) PV pass (barrier-free, single-wave jobs, double-buffered K/V regs)
  pv_kernel<<<4096, 64, 0, stream>>>(qbuf, ktile, vtile, invb, sufv, abuf, pbuf);

  // 6) reduce split partials
  reduce_kernel<<<512, 256, 0, stream>>>(pbuf, sufv, abuf);

  // 7) projection GEMM (BM=64 -> 512 blocks, 2/CU)
  gemm_kernel<1,64><<<dim3(1024/128, 4096/64), 256, 0, stream>>>(abuf, WpT, bp, 1024, nullptr, nullptr, nullptr, out);
}

// Round 9
// 198.935 us; speedup vs baseline: 1.0934x; 1.0934x over previous
//
#include <hip/hip_runtime.h>

#define DI __device__ __forceinline__

typedef __attribute__((ext_vector_type(8))) short s16x8;
typedef __attribute__((ext_vector_type(4))) short s16x4;
typedef __attribute__((ext_vector_type(4))) float f32x4;

DI unsigned short f2bf(float f){
  unsigned u = __float_as_uint(f);
  u = (u + 0x7FFFu + ((u >> 16) & 1u)) >> 16;
  return (unsigned short)u;
}
DI float bf2f(unsigned short h){
  return __uint_as_float(((unsigned)h) << 16);
}
DI float exp2i(float x){ float r; asm("v_exp_f32 %0, %1" : "=v"(r) : "v"(x)); return r; }

DI void gll16(const void* g, void* l){
  __builtin_amdgcn_global_load_lds((const __attribute__((address_space(1))) void*)g,
                                   (__attribute__((address_space(3))) void*)l, 16, 0, 0);
}

#define VMCNT(n) asm volatile("s_waitcnt vmcnt(" #n ")" ::: "memory")

// ---------------- elementwise fp32 -> bf16 ----------------
__global__ void cvt_kernel(const float* __restrict__ in, unsigned short* __restrict__ out, int n8){
  int i = blockIdx.x * blockDim.x + threadIdx.x;
  if (i >= n8) return;
  const float4* p = (const float4*)in + (size_t)i * 2;
  float4 a = p[0], b = p[1];
  s16x8 o;
  o[0] = (short)f2bf(a.x); o[1] = (short)f2bf(a.y); o[2] = (short)f2bf(a.z); o[3] = (short)f2bf(a.w);
  o[4] = (short)f2bf(b.x); o[5] = (short)f2bf(b.y); o[6] = (short)f2bf(b.z); o[7] = (short)f2bf(b.w);
  ((s16x8*)out)[i] = o;
}

// ---------------- transpose + convert: in fp32 [R][C] -> out bf16 [C][R] ----------------
__global__ void transpose_cvt(const float* __restrict__ in, unsigned short* __restrict__ out, int R, int C){
  __shared__ float t[32][33];
  int c0 = blockIdx.x * 32, r0 = blockIdx.y * 32;
  int tx = threadIdx.x, ty = threadIdx.y; // 32 x 8
  #pragma unroll
  for (int i = 0; i < 4; i++)
    t[ty + i*8][tx] = in[(size_t)(r0 + ty + i*8) * C + c0 + tx];
  __syncthreads();
  #pragma unroll
  for (int i = 0; i < 4; i++)
    out[(size_t)(c0 + ty + i*8) * R + r0 + tx] = f2bf(t[tx][ty + i*8]);
}

// ---------------- GEMM (m97 structure): C[M x N] = A[M x K] * Wt[N x K]^T + bias ----------------
// MODE 0 (BM=128): qkv -> qbuf rows (Q pre-scaled by log2e), ktile swz, vtile swz.
// MODE 1 (BM=64): proj -> fp32 out.
template<int MODE, int BM>
__launch_bounds__(256)
__global__ void gemm_kernel(const unsigned short* __restrict__ A,
                            const unsigned short* __restrict__ Wt,
                            const float* __restrict__ bias,
                            int N,
                            unsigned short* __restrict__ qb,
                            unsigned short* __restrict__ kb,
                            unsigned short* __restrict__ vt,
                            float* __restrict__ out)
{
  constexpr int MI = BM / 32;
  constexpr int AC = BM / 32;
  const int K = 1024;
  __shared__ unsigned short As[BM * 64];
  __shared__ unsigned short Bs[128 * 64];
  int m0 = blockIdx.y * BM, n0 = blockIdx.x * 128;
  int tid = threadIdx.x;
  int lane = tid & 63, w = tid >> 6;
  int row_l = lane & 15, kgrp = lane >> 4;
  int wm = (w >> 1) * (MI * 16), wn = (w & 1) * 64;

  const unsigned short* asrc[AC];
  const unsigned short* bsrc[4];
  int ldsoA[AC], ldsoB[4];
  int chunk = (lane & 7) ^ (lane >> 3);
  #pragma unroll
  for (int c4 = 0; c4 < AC; c4++){
    int r = c4*32 + w*8 + (lane >> 3);
    asrc[c4] = A + (size_t)(m0 + r) * K + chunk*8;
    ldsoA[c4] = (c4*32 + w*8) * 64;
  }
  #pragma unroll
  for (int c4 = 0; c4 < 4; c4++){
    int r = c4*32 + w*8 + (lane >> 3);
    bsrc[c4] = Wt + (size_t)(n0 + r) * K + chunk*8;
    ldsoB[c4] = (c4*32 + w*8) * 64;
  }
  int eA[MI], eB[4];
  #pragma unroll
  for (int i = 0; i < MI; i++){
    int ra = wm + i*16 + row_l;
    eA[i] = (ra*64 + kgrp*8) ^ ((ra & 7) << 3);
  }
  #pragma unroll
  for (int i = 0; i < 4; i++){
    int rb = wn + i*16 + row_l;
    eB[i] = (rb*64 + kgrp*8) ^ ((rb & 7) << 3);
  }

  f32x4 acc[MI][4];
  #pragma unroll
  for (int i = 0; i < MI; i++)
    #pragma unroll
    for (int j = 0; j < 4; j++)
      acc[i][j] = (f32x4){0.f, 0.f, 0.f, 0.f};

  for (int k0 = 0; k0 < K; k0 += 64){
    #pragma unroll
    for (int c4 = 0; c4 < AC; c4++)
      gll16(asrc[c4] + k0, (void*)(As + ldsoA[c4]));
    #pragma unroll
    for (int c4 = 0; c4 < 4; c4++)
      gll16(bsrc[c4] + k0, (void*)(Bs + ldsoB[c4]));
    __syncthreads();
    #pragma unroll
    for (int kc = 0; kc < 2; kc++){
      s16x8 af[MI], bfr[4];
      #pragma unroll
      for (int mi = 0; mi < MI; mi++)
        af[mi] = *(const s16x8*)&As[eA[mi] ^ (kc*32)];
      #pragma unroll
      for (int ni = 0; ni < 4; ni++)
        bfr[ni] = *(const s16x8*)&Bs[eB[ni] ^ (kc*32)];
      #pragma unroll
      for (int mi = 0; mi < MI; mi++)
        #pragma unroll
        for (int ni = 0; ni < 4; ni++)
          acc[mi][ni] = __builtin_amdgcn_mfma_f32_16x16x32_bf16(af[mi], bfr[ni], acc[mi][ni], 0, 0, 0);
    }
    __syncthreads();
  }

  #pragma unroll
  for (int mi = 0; mi < MI; mi++){
    #pragma unroll
    for (int ni = 0; ni < 4; ni++){
      #pragma unroll
      for (int j = 0; j < 4; j++){
        int gr = m0 + wm + mi*16 + kgrp*4 + j;
        int gc = n0 + wn + ni*16 + row_l;
        float v = acc[mi][ni][j] + bias[gc];
        if (MODE == 0){
          int h = gc / 192, cc = gc % 192;
          int b = gr >> 11, s = gr & 2047;
          if (cc < 64){
            // Q pre-scaled by log2(e): downstream uses raw v_exp_f32 (exp2)
            qb[(size_t)gr * 1024 + h*64 + cc] = f2bf(v * 1.44269504f);
          } else if (cc < 128){
            int d = cc - 64; int kt = s >> 6, kk = s & 63;
            kb[(size_t)((b*16 + h)*32 + kt) * 4096 + ((kk*64 + d) ^ ((kk & 7) << 3))] = f2bf(v);
          } else {
            int d = cc - 128; int kt = s >> 6, kk = s & 63;
            vt[(size_t)((b*16 + h)*32 + kt) * 4096 + ((d*64 + kk) ^ ((d & 7) << 3))] = f2bf(v);
          }
        } else {
          out[(size_t)gr * N + gc] = v;
        }
      }
    }
  }
}

// ---------------- V suffix sums (64-key granularity): sufv[bh][t in 0..32][64d] ----------------
__global__ void sufv_kernel(const unsigned short* __restrict__ vt, float* __restrict__ sufv){
  __shared__ float tot[4][64];
  int bh = blockIdx.x;                 // 32
  int tid = threadIdx.x;               // 256
  int tq = tid >> 6, d = tid & 63;
  const unsigned short* base = vt + (size_t)bh * 32 * 4096;
  float s[8];
  float run = 0.f;
  for (int j = 7; j >= 0; j--){
    int t = tq*8 + j;
    float rs = 0.f;
    #pragma unroll
    for (int c = 0; c < 8; c++){
      int idx = (d*64 + c*8) ^ ((d & 7) << 3);
      s16x8 v = *(const s16x8*)&base[(size_t)t*4096 + idx];
      #pragma unroll
      for (int e = 0; e < 8; e++) rs += bf2f((unsigned short)v[e]);
    }
    run += rs; s[j] = run;
  }
  tot[tq][d] = run;
  __syncthreads();
  float carry = 0.f;
  for (int t2 = tq+1; t2 < 4; t2++) carry += tot[t2][d];
  #pragma unroll
  for (int j = 0; j < 8; j++)
    sufv[((size_t)bh*33 + tq*8 + j)*64 + d] = s[j] + carry;
  if (tid < 64) sufv[((size_t)bh*33 + 32)*64 + tid] = 0.f;
}

// ---------------- D-pass: invb[b][q][k] (bf16) = 1 / sum_h exp(s_h(q,k)) over causal triangle ----------------
// kt-major tile enumeration + XCD swizzle; 4-buffer 2-deep LDS ring. Q pre-scaled -> raw exp2.
__launch_bounds__(256)
__global__ void dpass_kernel(const unsigned short* __restrict__ qbuf,
                             const unsigned short* __restrict__ kb,
                             unsigned short* __restrict__ invb)
{
  __shared__ unsigned short Kst[4][4096];
  int bid = blockIdx.x;                       // 1056 = 8 * 132
  int blk = (bid & 7) * 132 + (bid >> 3);     // XCD swizzle (bijective)
  int b = blk / 528, t = blk % 528;
  int kt = (int)(32.5f - sqrtf(1056.25f - 2.f*t));
  while (kt*(65-kt)/2 > t) kt--;
  while ((kt+1)*(64-kt)/2 <= t) kt++;
  int qt = kt + (t - kt*(65-kt)/2);

  int tid = threadIdx.x, lane = tid & 63, w = tid >> 6;
  int row_l = lane & 15, kgrp = lane >> 4;

  const unsigned short* ktb = kb + ((size_t)(b*16)*32 + kt) * 4096;
  int sgoff = (w*128 + lane)*8;

  auto stage = [&](int hh, int buf){
    const unsigned short* src = ktb + (size_t)hh * 131072;
    gll16(src + sgoff,       (void*)(&Kst[buf][0] + w*1024));
    gll16(src + sgoff + 512, (void*)(&Kst[buf][0] + w*1024 + 512));
  };

  int e0[4];
  #pragma unroll
  for (int ks = 0; ks < 4; ks++){
    int row = ks*16 + row_l;
    e0[ks] = (row*64 + kgrp*8) ^ ((row & 7) << 3);
  }

  stage(0, 0);
  stage(1, 1);

  f32x4 esum[4];
  #pragma unroll
  for (int ks = 0; ks < 4; ks++) esum[ks] = (f32x4){0.f,0.f,0.f,0.f};

  const unsigned short* qrow_p = qbuf + (size_t)(b*2048 + qt*64 + w*16 + row_l) * 1024;
  s16x8 qf0 = *(const s16x8*)&qrow_p[kgrp*8];
  s16x8 qf1 = *(const s16x8*)&qrow_p[32 + kgrp*8];

  for (int h = 0; h < 16; h++){
    s16x8 qn0, qn1;
    if (h < 15){
      qn0 = *(const s16x8*)&qrow_p[(h+1)*64 + kgrp*8];
      qn1 = *(const s16x8*)&qrow_p[(h+1)*64 + 32 + kgrp*8];
    }
    if (h + 2 < 16) stage(h+2, (h+2) & 3);
    __builtin_amdgcn_sched_barrier(0);
    if (h < 14)      VMCNT(8);
    else if (h < 15) VMCNT(6);
    else             VMCNT(2);
    __builtin_amdgcn_sched_barrier(0);
    __builtin_amdgcn_s_barrier();
    __builtin_amdgcn_sched_barrier(0);

    const unsigned short* kl = &Kst[h & 3][0];
    #pragma unroll
    for (int ks = 0; ks < 4; ks++){
      s16x8 a0 = *(const s16x8*)&kl[e0[ks]];
      s16x8 a1 = *(const s16x8*)&kl[e0[ks] ^ 32];
      f32x4 sc = __builtin_amdgcn_mfma_f32_16x16x32_bf16(a0, qf0, (f32x4){0.f,0.f,0.f,0.f}, 0, 0, 0);
      sc = __builtin_amdgcn_mfma_f32_16x16x32_bf16(a1, qf1, sc, 0, 0, 0);
      #pragma unroll
      for (int j = 0; j < 4; j++) esum[ks][j] += exp2i(sc[j]);
    }
    if (h < 15){ qf0 = qn0; qf1 = qn1; }
  }

  int qcol = qt*64 + w*16 + row_l;
  unsigned short* dst = invb + (size_t)b*4194304 + (size_t)qcol*2048 + kt*64 + kgrp*4;
  #pragma unroll
  for (int ks = 0; ks < 4; ks++){
    float r0 = 1.f/esum[ks][0], r1 = 1.f/esum[ks][1];
    float r2 = 1.f/esum[ks][2], r3 = 1.f/esum[ks][3];
    unsigned lo, hi;
    asm("v_cvt_pk_bf16_f32 %0, %1, %2" : "=v"(lo) : "v"(r0), "v"(r1));
    asm("v_cvt_pk_bf16_f32 %0, %1, %2" : "=v"(hi) : "v"(r2), "v"(r3));
    uint2 pk; pk.x = lo; pk.y = hi;
    *(uint2*)&dst[ks*16] = pk;
  }
}

// ---------------- PV-pass v5: solo-wave jobs, per-wave LDS K-ring (2x8KB, gll16), V in regs ----------------
// grid 4096 = (b, h, pair i, half, w) XCD-swizzled; 64 threads; LDS 18.7 KB -> 8 blocks/CU
// = 8 independent streams (2 waves/SIMD). ZERO barriers. One manual vmcnt per body for own-wave
// K staging (FIFO: newer-than-K(kt) = invd(kt)4 + V(kt)8 + K(kt+1)8 + invd(kt+1)4 = 24; tail 12).
// V/invD are register loads -> compiler auto-waitcnt. No VGPR double-buffer of K => no spill.
__launch_bounds__(64)
__global__ void pv_kernel(const unsigned short* __restrict__ qbuf,
                          const unsigned short* __restrict__ kb,
                          const unsigned short* __restrict__ vt,
                          const unsigned short* __restrict__ invb,
                          const float* __restrict__ sufv,
                          unsigned short* __restrict__ ab,
                          float* __restrict__ pb)
{
  __shared__ unsigned short Kst[2][4096];   // 2 x 8 KB ring
  __shared__ unsigned short Wsh[16 * 72];   // per-wave weight transpose buffer

  int bid = blockIdx.x;                              // 4096 = 8 * 512
  int blk = ((bid & 7) << 9) | (bid >> 3);           // XCD swizzle (bijective)
  int w    = blk & 3;
  int half = (blk >> 2) & 1;
  int i    = (blk >> 3) & 15;
  int h    = (blk >> 7) & 15;
  int b    = blk >> 11;
  int qsm = i, qbig = 31 - i;

  int lane = threadIdx.x & 63;
  int row_l = lane & 15, kgrp = lane >> 4;

  const unsigned short* KT = kb + (size_t)((b*16 + h)*32) * 4096;
  const unsigned short* VT = vt + (size_t)((b*16 + h)*32) * 4096;

  int eK[4];
  #pragma unroll
  for (int ks = 0; ks < 4; ks++)
    eK[ks] = ((ks*16 + row_l)*64 + kgrp*8) ^ ((row_l & 7) << 3);

  // stage full 8KB K tile: 8 x gll16 (1 KB each), linear copy (LDS image == global tile image)
  auto stageK = [&](int kt, int buf){
    const unsigned short* src = KT + (size_t)kt*4096 + lane*8;
    #pragma unroll
    for (int c = 0; c < 8; c++)
      gll16(src + c*512, (void*)(&Kst[buf][0] + c*512 + lane*8));
  };

  auto run = [&](int qt, int k0t, int k1t, int mode){
    int q0 = qt * 64;
    int qv = q0 + w*16 + row_l;
    const unsigned short* qrow_p = qbuf + (size_t)(b*2048 + qv) * 1024 + h*64;
    s16x8 qf0 = *(const s16x8*)&qrow_p[kgrp*8];
    s16x8 qf1 = *(const s16x8*)&qrow_p[32 + kgrp*8];
    const unsigned short* ivrow = invb + (size_t)b*4194304 + (size_t)qv*2048 + kgrp*4;

    f32x4 pvv[4];
    #pragma unroll
    for (int d = 0; d < 4; d++) pvv[d] = (f32x4){0.f,0.f,0.f,0.f};

    // prologue: [K(k0) stage x8][invd(k0) x4]
    stageK(k0t, 0);
    s16x4 i1[4];
    #pragma unroll
    for (int ks = 0; ks < 4; ks++) i1[ks] = *(const s16x4*)&ivrow[k0t*64 + ks*16];

    for (int kt = k0t; kt < k1t; kt++){
      int buf = (kt - k0t) & 1;
      bool nx = (kt + 1 < k1t);

      // issue region: V(kt) regs, K(kt+1) staging, invd(kt+1) regs
      const unsigned short* vp = VT + (size_t)kt*4096;
      s16x8 vr[8];
      #pragma unroll
      for (int kc = 0; kc < 2; kc++)
        #pragma unroll
        for (int dq = 0; dq < 4; dq++)
          vr[kc*4+dq] = *(const s16x8*)&vp[eK[dq] ^ (kc*32)];
      if (nx) stageK(kt+1, buf ^ 1);
      s16x4 icur[4];
      #pragma unroll
      for (int ks = 0; ks < 4; ks++) icur[ks] = i1[ks];
      if (nx){
        #pragma unroll
        for (int ks = 0; ks < 4; ks++) i1[ks] = *(const s16x4*)&ivrow[(kt+1)*64 + ks*16];
      }
      __builtin_amdgcn_sched_barrier(0);
      if (nx) VMCNT(24);      // K(kt) landed (24 newer ops in flight allowed)
      else    VMCNT(12);      // tail: only invd(kt)4 + V(kt)8 newer
      __builtin_amdgcn_sched_barrier(0);

      const unsigned short* kl = &Kst[buf][0];
      // QK^T (swapped: rows=key, cols=q); Q pre-scaled by log2e
      f32x4 sc[4];
      __builtin_amdgcn_s_setprio(1);
      #pragma unroll
      for (int ks = 0; ks < 4; ks++){
        s16x8 a0 = *(const s16x8*)&kl[eK[ks]];
        s16x8 a1 = *(const s16x8*)&kl[eK[ks] ^ 32];
        sc[ks] = __builtin_amdgcn_mfma_f32_16x16x32_bf16(a0, qf0, (f32x4){0.f,0.f,0.f,0.f}, 0, 0, 0);
        sc[ks] = __builtin_amdgcn_mfma_f32_16x16x32_bf16(a1, qf1, sc[ks], 0, 0, 0);
      }
      __builtin_amdgcn_s_setprio(0);

      // weights: w = exp2(s') * invD (masked -> exactly 1/16, diagonal tile only)
      if (kt == qt){
        int kbase = kt*64 + kgrp*4;
        #pragma unroll
        for (int ks = 0; ks < 4; ks++){
          #pragma unroll
          for (int j = 0; j < 4; j++){
            float wv = exp2i(sc[ks][j]) * bf2f((unsigned short)icur[ks][j]);
            sc[ks][j] = (kbase + ks*16 + j > qv) ? 0.0625f : wv;
          }
          unsigned lo, hi;
          asm("v_cvt_pk_bf16_f32 %0, %1, %2" : "=v"(lo) : "v"(sc[ks][0]), "v"(sc[ks][1]));
          asm("v_cvt_pk_bf16_f32 %0, %1, %2" : "=v"(hi) : "v"(sc[ks][2]), "v"(sc[ks][3]));
          uint2 pk2; pk2.x = lo; pk2.y = hi;
          *(uint2*)&Wsh[row_l*72 + ks*16 + kgrp*4] = pk2;
        }
      } else {
        #pragma unroll
        for (int ks = 0; ks < 4; ks++){
          #pragma unroll
          for (int j = 0; j < 4; j++)
            sc[ks][j] = exp2i(sc[ks][j]) * bf2f((unsigned short)icur[ks][j]);
          unsigned lo, hi;
          asm("v_cvt_pk_bf16_f32 %0, %1, %2" : "=v"(lo) : "v"(sc[ks][0]), "v"(sc[ks][1]));
          asm("v_cvt_pk_bf16_f32 %0, %1, %2" : "=v"(hi) : "v"(sc[ks][2]), "v"(sc[ks][3]));
          uint2 pk2; pk2.x = lo; pk2.y = hi;
          *(uint2*)&Wsh[row_l*72 + ks*16 + kgrp*4] = pk2;
        }
      }

      // PV (same-wave LDS write->read; compiler lgkm ordering)
      __builtin_amdgcn_s_setprio(1);
      #pragma unroll
      for (int kc = 0; kc < 2; kc++){
        s16x8 af = *(const s16x8*)&Wsh[row_l*72 + kc*32 + kgrp*8];
        #pragma unroll
        for (int dq = 0; dq < 4; dq++)
          pvv[dq] = __builtin_amdgcn_mfma_f32_16x16x32_bf16(af, vr[kc*4+dq], pvv[dq], 0, 0, 0);
      }
      __builtin_amdgcn_s_setprio(0);
    }

    // epilogue: out rows q = q0 + w*16 + kgrp*4 + j; cols d = dq*16 + row_l
    if (mode == 0){
      int tsuf = qt + 1;
      #pragma unroll
      for (int dq = 0; dq < 4; dq++){
        int d = dq*16 + row_l;
        float suf = sufv[((size_t)(b*16 + h)*33 + tsuf)*64 + d];
        #pragma unroll
        for (int j = 0; j < 4; j++){
          int qo = q0 + w*16 + kgrp*4 + j;
          ab[(size_t)(b*2048 + qo)*1024 + h*64 + d] = f2bf(pvv[dq][j] + 0.0625f * suf);
        }
      }
    } else {
      float* pr = pb + ((size_t)((b*16 + h)*16 + i)*2 + (mode - 1)) * 4096;
      #pragma unroll
      for (int dq = 0; dq < 4; dq++){
        int d = dq*16 + row_l;
        #pragma unroll
        for (int j = 0; j < 4; j++)
          pr[(w*16 + kgrp*4 + j)*64 + d] = pvv[dq][j];
      }
    }
  };

  if (half == 0){
    run(qsm, 0, i + 1, 0);
    run(qbig, 0, 16 - i, 1);
  } else {
    run(qbig, 16 - i, 32 - i, 2);
  }
}

// ---------------- reduce split partials + suffix tail -> abuf ----------------
__global__ void reduce_kernel(const float* __restrict__ pb,
                              const float* __restrict__ sufv,
                              unsigned short* __restrict__ ab)
{
  int blk = blockIdx.x;               // 512 = (b,h,i)
  int b = blk >> 8, rr = blk & 255;
  int h = rr >> 4, i = rr & 15;
  int qbig = 31 - i, tsuf = 32 - i;
  int t = threadIdx.x;
  int q = t >> 2, dbase = (t & 3) * 16;
  const float* p0 = pb + ((size_t)((b*16 + h)*16 + i)*2 + 0)*4096 + q*64 + dbase;
  const float* p1 = p0 + 4096;
  const float* sf = sufv + ((size_t)(b*16 + h)*33 + tsuf)*64 + dbase;
  unsigned short* op = ab + (size_t)(b*2048 + qbig*64 + q)*1024 + h*64 + dbase;
  #pragma unroll
  for (int e = 0; e < 4; e++){
    float4 a = *(const float4*)(p0 + e*4);
    float4 bb = *(const float4*)(p1 + e*4);
    float4 s = *(const float4*)(sf + e*4);
    unsigned short o[4];
    o[0] = f2bf(a.x + bb.x + 0.0625f * s.x);
    o[1] = f2bf(a.y + bb.y + 0.0625f * s.y);
    o[2] = f2bf(a.z + bb.z + 0.0625f * s.z);
    o[3] = f2bf(a.w + bb.w + 0.0625f * s.w);
    *(s16x4*)(op + e*4) = *(s16x4*)o;
  }
}

// ---------------- host ----------------
extern "C" void kernel_launch(void* const* d_in, const int* in_sizes, int n_in,
                              void* d_out, int out_size, void* d_ws, size_t ws_size,
                              hipStream_t stream) {
  (void)in_sizes; (void)n_in; (void)out_size; (void)ws_size;
  const float* x  = (const float*)d_in[0];
  const float* Wa = (const float*)d_in[1];
  const float* ba = (const float*)d_in[2];
  const float* Wp = (const float*)d_in[3];
  const float* bp = (const float*)d_in[4];
  float* out = (float*)d_out;

  char* ws = (char*)d_ws;
  size_t off = 0;
  auto alloc = [&](size_t bytes) -> void* {
    void* p = ws + off;
    off += (bytes + 255) & ~(size_t)255;
    return p;
  };
  // region A (16 MB): xb (8 MB) + WaT (6 MB) alias pbuf — both dead before pv_kernel writes partials
  float* pbuf          = (float*)alloc((size_t)16*1024*1024);
  unsigned short* xb   = (unsigned short*)((char*)pbuf);
  unsigned short* WaT  = (unsigned short*)((char*)pbuf + (size_t)4096*1024*2);
  unsigned short* WpT  = (unsigned short*)alloc((size_t)1024*1024*2);
  unsigned short* qbuf = (unsigned short*)alloc((size_t)4096*1024*2);
  unsigned short* ktile= (unsigned short*)alloc((size_t)4096*1024*2);
  unsigned short* vtile= (unsigned short*)alloc((size_t)4096*1024*2);
  unsigned short* abuf = (unsigned short*)alloc((size_t)4096*1024*2);
  unsigned short* invb = (unsigned short*)alloc((size_t)2*2048*2048*2); // bf16 invD
  float* sufv          = (float*)alloc((size_t)32*33*64*4);

  // 1) conversions
  cvt_kernel<<<2048, 256, 0, stream>>>(x, xb, 4096*1024/8);
  transpose_cvt<<<dim3(3072/32, 1024/32), dim3(32, 8), 0, stream>>>(Wa, WaT, 1024, 3072);
  transpose_cvt<<<dim3(1024/32, 1024/32), dim3(32, 8), 0, stream>>>(Wp, WpT, 1024, 1024);

  // 2) QKV GEMM -> qbuf / ktile / vtile
  gemm_kernel<0,128><<<dim3(24, 32), 256, 0, stream>>>(xb, WaT, ba, 3072, qbuf, ktile, vtile, nullptr);

  // 3) V suffix sums
  sufv_kernel<<<32, 256, 0, stream>>>(vtile, sufv);

  // 4) denominator pass (bf16 invD)
  dpass_kernel<<<1056, 256, 0, stream>>>(qbuf, ktile, invb);

  // 5) PV pass (solo-wave, per-wave LDS K-ring, V in regs, zero barriers)
  pv_kernel<<<4096, 64, 0, stream>>>(qbuf, ktile, vtile, invb, sufv, abuf, pbuf);

  // 6) reduce split partials
  reduce_kernel<<<512, 256, 0, stream>>>(pbuf, sufv, abuf);

  // 7) projection GEMM (BM=64 -> 512 blocks, 2/CU)
  gemm_kernel<1,64><<<dim3(1024/128, 4096/64), 256, 0, stream>>>(abuf, WpT, bp, 1024, nullptr, nullptr, nullptr, out);
}

// Round 10
// 180.580 us; speedup vs baseline: 1.2045x; 1.1016x over previous
//
#include <hip/hip_runtime.h>

#define DI __device__ __forceinline__

typedef __attribute__((ext_vector_type(8))) short s16x8;
typedef __attribute__((ext_vector_type(4))) short s16x4;
typedef __attribute__((ext_vector_type(4))) float f32x4;

DI unsigned short f2bf(float f){
  unsigned u = __float_as_uint(f);
  u = (u + 0x7FFFu + ((u >> 16) & 1u)) >> 16;
  return (unsigned short)u;
}
DI float bf2f(unsigned short h){
  return __uint_as_float(((unsigned)h) << 16);
}
DI float exp2i(float x){ float r; asm("v_exp_f32 %0, %1" : "=v"(r) : "v"(x)); return r; }

DI void gll16(const void* g, void* l){
  __builtin_amdgcn_global_load_lds((const __attribute__((address_space(1))) void*)g,
                                   (__attribute__((address_space(3))) void*)l, 16, 0, 0);
}

#define VMCNT(n) asm volatile("s_waitcnt vmcnt(" #n ")" ::: "memory")

// ---------------- elementwise fp32 -> bf16 ----------------
__global__ void cvt_kernel(const float* __restrict__ in, unsigned short* __restrict__ out, int n8){
  int i = blockIdx.x * blockDim.x + threadIdx.x;
  if (i >= n8) return;
  const float4* p = (const float4*)in + (size_t)i * 2;
  float4 a = p[0], b = p[1];
  s16x8 o;
  o[0] = (short)f2bf(a.x); o[1] = (short)f2bf(a.y); o[2] = (short)f2bf(a.z); o[3] = (short)f2bf(a.w);
  o[4] = (short)f2bf(b.x); o[5] = (short)f2bf(b.y); o[6] = (short)f2bf(b.z); o[7] = (short)f2bf(b.w);
  ((s16x8*)out)[i] = o;
}

// ---------------- transpose + convert: in fp32 [R][C] -> out bf16 [C][R] ----------------
__global__ void transpose_cvt(const float* __restrict__ in, unsigned short* __restrict__ out, int R, int C){
  __shared__ float t[32][33];
  int c0 = blockIdx.x * 32, r0 = blockIdx.y * 32;
  int tx = threadIdx.x, ty = threadIdx.y; // 32 x 8
  #pragma unroll
  for (int i = 0; i < 4; i++)
    t[ty + i*8][tx] = in[(size_t)(r0 + ty + i*8) * C + c0 + tx];
  __syncthreads();
  #pragma unroll
  for (int i = 0; i < 4; i++)
    out[(size_t)(c0 + ty + i*8) * R + r0 + tx] = f2bf(t[tx][ty + i*8]);
}

// ---------------- GEMM (m97 structure): C[M x N] = A[M x K] * Wt[N x K]^T + bias ----------------
// MODE 0 (BM=128): qkv -> qbuf rows (Q pre-scaled by log2e), ktile swz, vtile swz.
// MODE 1 (BM=64): proj -> fp32 out.
template<int MODE, int BM>
__launch_bounds__(256)
__global__ void gemm_kernel(const unsigned short* __restrict__ A,
                            const unsigned short* __restrict__ Wt,
                            const float* __restrict__ bias,
                            int N,
                            unsigned short* __restrict__ qb,
                            unsigned short* __restrict__ kb,
                            unsigned short* __restrict__ vt,
                            float* __restrict__ out)
{
  constexpr int MI = BM / 32;
  constexpr int AC = BM / 32;
  const int K = 1024;
  __shared__ unsigned short As[BM * 64];
  __shared__ unsigned short Bs[128 * 64];
  int m0 = blockIdx.y * BM, n0 = blockIdx.x * 128;
  int tid = threadIdx.x;
  int lane = tid & 63, w = tid >> 6;
  int row_l = lane & 15, kgrp = lane >> 4;
  int wm = (w >> 1) * (MI * 16), wn = (w & 1) * 64;

  const unsigned short* asrc[AC];
  const unsigned short* bsrc[4];
  int ldsoA[AC], ldsoB[4];
  int chunk = (lane & 7) ^ (lane >> 3);
  #pragma unroll
  for (int c4 = 0; c4 < AC; c4++){
    int r = c4*32 + w*8 + (lane >> 3);
    asrc[c4] = A + (size_t)(m0 + r) * K + chunk*8;
    ldsoA[c4] = (c4*32 + w*8) * 64;
  }
  #pragma unroll
  for (int c4 = 0; c4 < 4; c4++){
    int r = c4*32 + w*8 + (lane >> 3);
    bsrc[c4] = Wt + (size_t)(n0 + r) * K + chunk*8;
    ldsoB[c4] = (c4*32 + w*8) * 64;
  }
  int eA[MI], eB[4];
  #pragma unroll
  for (int i = 0; i < MI; i++){
    int ra = wm + i*16 + row_l;
    eA[i] = (ra*64 + kgrp*8) ^ ((ra & 7) << 3);
  }
  #pragma unroll
  for (int i = 0; i < 4; i++){
    int rb = wn + i*16 + row_l;
    eB[i] = (rb*64 + kgrp*8) ^ ((rb & 7) << 3);
  }

  f32x4 acc[MI][4];
  #pragma unroll
  for (int i = 0; i < MI; i++)
    #pragma unroll
    for (int j = 0; j < 4; j++)
      acc[i][j] = (f32x4){0.f, 0.f, 0.f, 0.f};

  for (int k0 = 0; k0 < K; k0 += 64){
    #pragma unroll
    for (int c4 = 0; c4 < AC; c4++)
      gll16(asrc[c4] + k0, (void*)(As + ldsoA[c4]));
    #pragma unroll
    for (int c4 = 0; c4 < 4; c4++)
      gll16(bsrc[c4] + k0, (void*)(Bs + ldsoB[c4]));
    __syncthreads();
    #pragma unroll
    for (int kc = 0; kc < 2; kc++){
      s16x8 af[MI], bfr[4];
      #pragma unroll
      for (int mi = 0; mi < MI; mi++)
        af[mi] = *(const s16x8*)&As[eA[mi] ^ (kc*32)];
      #pragma unroll
      for (int ni = 0; ni < 4; ni++)
        bfr[ni] = *(const s16x8*)&Bs[eB[ni] ^ (kc*32)];
      #pragma unroll
      for (int mi = 0; mi < MI; mi++)
        #pragma unroll
        for (int ni = 0; ni < 4; ni++)
          acc[mi][ni] = __builtin_amdgcn_mfma_f32_16x16x32_bf16(af[mi], bfr[ni], acc[mi][ni], 0, 0, 0);
    }
    __syncthreads();
  }

  #pragma unroll
  for (int mi = 0; mi < MI; mi++){
    #pragma unroll
    for (int ni = 0; ni < 4; ni++){
      #pragma unroll
      for (int j = 0; j < 4; j++){
        int gr = m0 + wm + mi*16 + kgrp*4 + j;
        int gc = n0 + wn + ni*16 + row_l;
        float v = acc[mi][ni][j] + bias[gc];
        if (MODE == 0){
          int h = gc / 192, cc = gc % 192;
          int b = gr >> 11, s = gr & 2047;
          if (cc < 64){
            // Q pre-scaled by log2(e): downstream uses raw v_exp_f32 (exp2)
            qb[(size_t)gr * 1024 + h*64 + cc] = f2bf(v * 1.44269504f);
          } else if (cc < 128){
            int d = cc - 64; int kt = s >> 6, kk = s & 63;
            kb[(size_t)((b*16 + h)*32 + kt) * 4096 + ((kk*64 + d) ^ ((kk & 7) << 3))] = f2bf(v);
          } else {
            int d = cc - 128; int kt = s >> 6, kk = s & 63;
            vt[(size_t)((b*16 + h)*32 + kt) * 4096 + ((d*64 + kk) ^ ((d & 7) << 3))] = f2bf(v);
          }
        } else {
          out[(size_t)gr * N + gc] = v;
        }
      }
    }
  }
}

// ---------------- V suffix sums (64-key granularity): sufv[bh][t in 0..32][64d] ----------------
__global__ void sufv_kernel(const unsigned short* __restrict__ vt, float* __restrict__ sufv){
  __shared__ float tot[4][64];
  int bh = blockIdx.x;                 // 32
  int tid = threadIdx.x;               // 256
  int tq = tid >> 6, d = tid & 63;
  const unsigned short* base = vt + (size_t)bh * 32 * 4096;
  float s[8];
  float run = 0.f;
  for (int j = 7; j >= 0; j--){
    int t = tq*8 + j;
    float rs = 0.f;
    #pragma unroll
    for (int c = 0; c < 8; c++){
      int idx = (d*64 + c*8) ^ ((d & 7) << 3);
      s16x8 v = *(const s16x8*)&base[(size_t)t*4096 + idx];
      #pragma unroll
      for (int e = 0; e < 8; e++) rs += bf2f((unsigned short)v[e]);
    }
    run += rs; s[j] = run;
  }
  tot[tq][d] = run;
  __syncthreads();
  float carry = 0.f;
  for (int t2 = tq+1; t2 < 4; t2++) carry += tot[t2][d];
  #pragma unroll
  for (int j = 0; j < 8; j++)
    sufv[((size_t)bh*33 + tq*8 + j)*64 + d] = s[j] + carry;
  if (tid < 64) sufv[((size_t)bh*33 + 32)*64 + tid] = 0.f;
}

// ---------------- D-pass: invb[b][q][k] (bf16) = 1 / sum_h exp(s_h(q,k)) over causal triangle ----------------
__launch_bounds__(256)
__global__ void dpass_kernel(const unsigned short* __restrict__ qbuf,
                             const unsigned short* __restrict__ kb,
                             unsigned short* __restrict__ invb)
{
  __shared__ unsigned short Kst[4][4096];
  int bid = blockIdx.x;                       // 1056 = 8 * 132
  int blk = (bid & 7) * 132 + (bid >> 3);     // XCD swizzle (bijective)
  int b = blk / 528, t = blk % 528;
  int kt = (int)(32.5f - sqrtf(1056.25f - 2.f*t));
  while (kt*(65-kt)/2 > t) kt--;
  while ((kt+1)*(64-kt)/2 <= t) kt++;
  int qt = kt + (t - kt*(65-kt)/2);

  int tid = threadIdx.x, lane = tid & 63, w = tid >> 6;
  int row_l = lane & 15, kgrp = lane >> 4;

  const unsigned short* ktb = kb + ((size_t)(b*16)*32 + kt) * 4096;
  int sgoff = (w*128 + lane)*8;

  auto stage = [&](int hh, int buf){
    const unsigned short* src = ktb + (size_t)hh * 131072;
    gll16(src + sgoff,       (void*)(&Kst[buf][0] + w*1024));
    gll16(src + sgoff + 512, (void*)(&Kst[buf][0] + w*1024 + 512));
  };

  int e0[4];
  #pragma unroll
  for (int ks = 0; ks < 4; ks++){
    int row = ks*16 + row_l;
    e0[ks] = (row*64 + kgrp*8) ^ ((row & 7) << 3);
  }

  stage(0, 0);
  stage(1, 1);

  f32x4 esum[4];
  #pragma unroll
  for (int ks = 0; ks < 4; ks++) esum[ks] = (f32x4){0.f,0.f,0.f,0.f};

  const unsigned short* qrow_p = qbuf + (size_t)(b*2048 + qt*64 + w*16 + row_l) * 1024;
  s16x8 qf0 = *(const s16x8*)&qrow_p[kgrp*8];
  s16x8 qf1 = *(const s16x8*)&qrow_p[32 + kgrp*8];

  for (int h = 0; h < 16; h++){
    s16x8 qn0, qn1;
    if (h < 15){
      qn0 = *(const s16x8*)&qrow_p[(h+1)*64 + kgrp*8];
      qn1 = *(const s16x8*)&qrow_p[(h+1)*64 + 32 + kgrp*8];
    }
    if (h + 2 < 16) stage(h+2, (h+2) & 3);
    __builtin_amdgcn_sched_barrier(0);
    if (h < 14)      VMCNT(8);
    else if (h < 15) VMCNT(6);
    else             VMCNT(2);
    __builtin_amdgcn_sched_barrier(0);
    __builtin_amdgcn_s_barrier();
    __builtin_amdgcn_sched_barrier(0);

    const unsigned short* kl = &Kst[h & 3][0];
    #pragma unroll
    for (int ks = 0; ks < 4; ks++){
      s16x8 a0 = *(const s16x8*)&kl[e0[ks]];
      s16x8 a1 = *(const s16x8*)&kl[e0[ks] ^ 32];
      f32x4 sc = __builtin_amdgcn_mfma_f32_16x16x32_bf16(a0, qf0, (f32x4){0.f,0.f,0.f,0.f}, 0, 0, 0);
      sc = __builtin_amdgcn_mfma_f32_16x16x32_bf16(a1, qf1, sc, 0, 0, 0);
      #pragma unroll
      for (int j = 0; j < 4; j++) esum[ks][j] += exp2i(sc[j]);
    }
    if (h < 15){ qf0 = qn0; qf1 = qn1; }
  }

  int qcol = qt*64 + w*16 + row_l;
  unsigned short* dst = invb + (size_t)b*4194304 + (size_t)qcol*2048 + kt*64 + kgrp*4;
  #pragma unroll
  for (int ks = 0; ks < 4; ks++){
    float r0 = 1.f/esum[ks][0], r1 = 1.f/esum[ks][1];
    float r2 = 1.f/esum[ks][2], r3 = 1.f/esum[ks][3];
    unsigned lo, hi;
    asm("v_cvt_pk_bf16_f32 %0, %1, %2" : "=v"(lo) : "v"(r0), "v"(r1));
    asm("v_cvt_pk_bf16_f32 %0, %1, %2" : "=v"(hi) : "v"(r2), "v"(r3));
    uint2 pk; pk.x = lo; pk.y = hi;
    *(uint2*)&dst[ks*16] = pk;
  }
}

// ---------------- PV-pass v6: proven 4-wave one-barrier skeleton, static LDS ----------------
// K ring 4 (lead-2, staged pre-barrier), V ring 2 (lead-1, staged POST-barrier so the single
// barrier protects overwrite), per-wave Ws. 57.75 KB static LDS -> 2 blocks/CU.
// FIFO audit (newer-than-V(kt) at VMCNT): first iter 12/10/4; steady 6/4/0.
// grid 1024 = (b, h, pair i, half) XCD-swizzled.
__launch_bounds__(256)
__global__ void pv_kernel(const unsigned short* __restrict__ qbuf,
                          const unsigned short* __restrict__ kb,
                          const unsigned short* __restrict__ vt,
                          const unsigned short* __restrict__ invb,
                          const float* __restrict__ sufv,
                          unsigned short* __restrict__ ab,
                          float* __restrict__ pb)
{
  __shared__ unsigned short Kst[4][4096];   // 32 KB
  __shared__ unsigned short Vst[2][4096];   // 16 KB
  __shared__ unsigned short Wsh[4][1152];   // 9 KB (per-wave private)

  int blk = ((blockIdx.x & 7) << 7) + (blockIdx.x >> 3);   // XCD swizzle, 1024 = 8*128
  int b = blk >> 9;
  int r = blk & 511;
  int h = r >> 5;
  int r2 = r & 31;
  int i = r2 >> 1, half = r2 & 1;
  int qsm = i, qbig = 31 - i;

  int tid = threadIdx.x, lane = tid & 63, w = tid >> 6;
  int row_l = lane & 15, kgrp = lane >> 4;

  const unsigned short* KT = kb + (size_t)((b*16 + h)*32) * 4096;
  const unsigned short* VT = vt + (size_t)((b*16 + h)*32) * 4096;
  int sgoff = (w*128 + lane)*8;
  unsigned short* Wsw = &Wsh[w][0];

  int eK[4];
  #pragma unroll
  for (int ks = 0; ks < 4; ks++){
    int row = ks*16 + row_l;
    eK[ks] = (row*64 + kgrp*8) ^ ((row & 7) << 3);
  }

  auto stageK = [&](int kt, int buf){
    gll16(KT + (size_t)kt*4096 + sgoff,       (void*)(&Kst[buf][0] + w*1024));
    gll16(KT + (size_t)kt*4096 + sgoff + 512, (void*)(&Kst[buf][0] + w*1024 + 512));
  };
  auto stageV = [&](int kt, int buf){
    gll16(VT + (size_t)kt*4096 + sgoff,       (void*)(&Vst[buf][0] + w*1024));
    gll16(VT + (size_t)kt*4096 + sgoff + 512, (void*)(&Vst[buf][0] + w*1024 + 512));
  };

  auto run = [&](int qt, int k0t, int k1t, int mode){
    int q0 = qt * 64;
    int qv = q0 + w*16 + row_l;
    const unsigned short* qrow_p = qbuf + (size_t)(b*2048 + qv) * 1024 + h*64;
    s16x8 qf0 = *(const s16x8*)&qrow_p[kgrp*8];
    s16x8 qf1 = *(const s16x8*)&qrow_p[32 + kgrp*8];
    const unsigned short* ivrow = invb + (size_t)b*4194304 + (size_t)qv*2048 + kgrp*4;

    f32x4 pvv[4];
    #pragma unroll
    for (int d = 0; d < 4; d++) pvv[d] = (f32x4){0.f,0.f,0.f,0.f};

    __syncthreads();                     // previous segment fully done with all buffers
    // prologue: K(k0)[2], V(k0)[2], inv(k0)[4], K(k0+1)[2]
    stageK(k0t, k0t & 3);
    stageV(k0t, k0t & 1);
    s16x4 i1[4];
    #pragma unroll
    for (int ks = 0; ks < 4; ks++) i1[ks] = *(const s16x4*)&ivrow[k0t*64 + ks*16];
    if (k0t + 1 < k1t) stageK(k0t+1, (k0t+1) & 3);

    for (int kt = k0t; kt < k1t; kt++){
      bool nx1 = (kt + 1 < k1t), nx2 = (kt + 2 < k1t);
      bool first = (kt == k0t);

      s16x4 icur[4];
      #pragma unroll
      for (int ks = 0; ks < 4; ks++) icur[ks] = i1[ks];
      if (nx1){
        #pragma unroll
        for (int ks = 0; ks < 4; ks++) i1[ks] = *(const s16x4*)&ivrow[(kt+1)*64 + ks*16];
      }
      if (nx2) stageK(kt+2, (kt+2) & 3);          // overwrites K(kt-2): read finished pre-barrier(kt-1)

      __builtin_amdgcn_sched_barrier(0);
      // newer-than-V(kt) op count (FIFO audit)
      if (first){
        if (nx2)      VMCNT(12);
        else if (nx1) VMCNT(10);
        else          VMCNT(4);
      } else {
        if (nx2)      VMCNT(6);
        else if (nx1) VMCNT(4);
        else          VMCNT(0);
      }
      __builtin_amdgcn_sched_barrier(0);
      __builtin_amdgcn_s_barrier();               // publish K(kt), V(kt)
      __builtin_amdgcn_sched_barrier(0);

      if (nx1) stageV(kt+1, (kt+1) & 1);          // post-barrier: overwrite of V(kt-1) is safe

      const unsigned short* kl = &Kst[kt & 3][0];
      const unsigned short* vl = &Vst[kt & 1][0];
      // QK^T (swapped: rows=key, cols=q); Q pre-scaled by log2e
      f32x4 sc[4];
      #pragma unroll
      for (int ks = 0; ks < 4; ks++){
        s16x8 a0 = *(const s16x8*)&kl[eK[ks]];
        s16x8 a1 = *(const s16x8*)&kl[eK[ks] ^ 32];
        sc[ks] = __builtin_amdgcn_mfma_f32_16x16x32_bf16(a0, qf0, (f32x4){0.f,0.f,0.f,0.f}, 0, 0, 0);
        sc[ks] = __builtin_amdgcn_mfma_f32_16x16x32_bf16(a1, qf1, sc[ks], 0, 0, 0);
      }

      // weights: w = exp2(s') * invD (masked -> exactly 1/16, diagonal tile only)
      if (kt == qt){
        int kbase = kt*64 + kgrp*4;
        #pragma unroll
        for (int ks = 0; ks < 4; ks++){
          #pragma unroll
          for (int j = 0; j < 4; j++){
            float wv = exp2i(sc[ks][j]) * bf2f((unsigned short)icur[ks][j]);
            sc[ks][j] = (kbase + ks*16 + j > qv) ? 0.0625f : wv;
          }
          unsigned lo, hi;
          asm("v_cvt_pk_bf16_f32 %0, %1, %2" : "=v"(lo) : "v"(sc[ks][0]), "v"(sc[ks][1]));
          asm("v_cvt_pk_bf16_f32 %0, %1, %2" : "=v"(hi) : "v"(sc[ks][2]), "v"(sc[ks][3]));
          uint2 pk2; pk2.x = lo; pk2.y = hi;
          *(uint2*)&Wsw[row_l*72 + ks*16 + kgrp*4] = pk2;
        }
      } else {
        #pragma unroll
        for (int ks = 0; ks < 4; ks++){
          #pragma unroll
          for (int j = 0; j < 4; j++)
            sc[ks][j] = exp2i(sc[ks][j]) * bf2f((unsigned short)icur[ks][j]);
          unsigned lo, hi;
          asm("v_cvt_pk_bf16_f32 %0, %1, %2" : "=v"(lo) : "v"(sc[ks][0]), "v"(sc[ks][1]));
          asm("v_cvt_pk_bf16_f32 %0, %1, %2" : "=v"(hi) : "v"(sc[ks][2]), "v"(sc[ks][3]));
          uint2 pk2; pk2.x = lo; pk2.y = hi;
          *(uint2*)&Wsw[row_l*72 + ks*16 + kgrp*4] = pk2;
        }
      }

      // PV (per-wave private Ws: same-wave lgkm ordering, no barrier)
      #pragma unroll
      for (int kc = 0; kc < 2; kc++){
        s16x8 af = *(const s16x8*)&Wsw[row_l*72 + kc*32 + kgrp*8];
        #pragma unroll
        for (int dq = 0; dq < 4; dq++){
          s16x8 vf = *(const s16x8*)&vl[eK[dq] ^ (kc*32)];
          pvv[dq] = __builtin_amdgcn_mfma_f32_16x16x32_bf16(af, vf, pvv[dq], 0, 0, 0);
        }
      }
    }

    // epilogue: out rows q = q0 + w*16 + kgrp*4 + j; cols d = dq*16 + row_l
    if (mode == 0){
      int tsuf = qt + 1;
      #pragma unroll
      for (int dq = 0; dq < 4; dq++){
        int d = dq*16 + row_l;
        float suf = sufv[((size_t)(b*16 + h)*33 + tsuf)*64 + d];
        #pragma unroll
        for (int j = 0; j < 4; j++){
          int qo = q0 + w*16 + kgrp*4 + j;
          ab[(size_t)(b*2048 + qo)*1024 + h*64 + d] = f2bf(pvv[dq][j] + 0.0625f * suf);
        }
      }
    } else {
      float* pr = pb + ((size_t)((b*16 + h)*16 + i)*2 + (mode - 1)) * 4096;
      #pragma unroll
      for (int dq = 0; dq < 4; dq++){
        int d = dq*16 + row_l;
        #pragma unroll
        for (int j = 0; j < 4; j++)
          pr[(w*16 + kgrp*4 + j)*64 + d] = pvv[dq][j];
      }
    }
  };

  if (half == 0){
    run(qsm, 0, i + 1, 0);
    run(qbig, 0, 16 - i, 1);
  } else {
    run(qbig, 16 - i, 32 - i, 2);
  }
}

// ---------------- reduce split partials + suffix tail -> abuf ----------------
__global__ void reduce_kernel(const float* __restrict__ pb,
                              const float* __restrict__ sufv,
                              unsigned short* __restrict__ ab)
{
  int blk = blockIdx.x;               // 512 = (b,h,i)
  int b = blk >> 8, rr = blk & 255;
  int h = rr >> 4, i = rr & 15;
  int qbig = 31 - i, tsuf = 32 - i;
  int t = threadIdx.x;
  int q = t >> 2, dbase = (t & 3) * 16;
  const float* p0 = pb + ((size_t)((b*16 + h)*16 + i)*2 + 0)*4096 + q*64 + dbase;
  const float* p1 = p0 + 4096;
  const float* sf = sufv + ((size_t)(b*16 + h)*33 + tsuf)*64 + dbase;
  unsigned short* op = ab + (size_t)(b*2048 + qbig*64 + q)*1024 + h*64 + dbase;
  #pragma unroll
  for (int e = 0; e < 4; e++){
    float4 a = *(const float4*)(p0 + e*4);
    float4 bb = *(const float4*)(p1 + e*4);
    float4 s = *(const float4*)(sf + e*4);
    unsigned short o[4];
    o[0] = f2bf(a.x + bb.x + 0.0625f * s.x);
    o[1] = f2bf(a.y + bb.y + 0.0625f * s.y);
    o[2] = f2bf(a.z + bb.z + 0.0625f * s.z);
    o[3] = f2bf(a.w + bb.w + 0.0625f * s.w);
    *(s16x4*)(op + e*4) = *(s16x4*)o;
  }
}

// ---------------- host ----------------
extern "C" void kernel_launch(void* const* d_in, const int* in_sizes, int n_in,
                              void* d_out, int out_size, void* d_ws, size_t ws_size,
                              hipStream_t stream) {
  (void)in_sizes; (void)n_in; (void)out_size; (void)ws_size;
  const float* x  = (const float*)d_in[0];
  const float* Wa = (const float*)d_in[1];
  const float* ba = (const float*)d_in[2];
  const float* Wp = (const float*)d_in[3];
  const float* bp = (const float*)d_in[4];
  float* out = (float*)d_out;

  char* ws = (char*)d_ws;
  size_t off = 0;
  auto alloc = [&](size_t bytes) -> void* {
    void* p = ws + off;
    off += (bytes + 255) & ~(size_t)255;
    return p;
  };
  // region A (16 MB): xb (8 MB) + WaT (6 MB) alias pbuf — both dead before pv_kernel writes partials
  float* pbuf          = (float*)alloc((size_t)16*1024*1024);
  unsigned short* xb   = (unsigned short*)((char*)pbuf);
  unsigned short* WaT  = (unsigned short*)((char*)pbuf + (size_t)4096*1024*2);
  unsigned short* WpT  = (unsigned short*)alloc((size_t)1024*1024*2);
  unsigned short* qbuf = (unsigned short*)alloc((size_t)4096*1024*2);
  unsigned short* ktile= (unsigned short*)alloc((size_t)4096*1024*2);
  unsigned short* vtile= (unsigned short*)alloc((size_t)4096*1024*2);
  unsigned short* abuf = (unsigned short*)alloc((size_t)4096*1024*2);
  unsigned short* invb = (unsigned short*)alloc((size_t)2*2048*2048*2); // bf16 invD
  float* sufv          = (float*)alloc((size_t)32*33*64*4);

  // 1) conversions
  cvt_kernel<<<2048, 256, 0, stream>>>(x, xb, 4096*1024/8);
  transpose_cvt<<<dim3(3072/32, 1024/32), dim3(32, 8), 0, stream>>>(Wa, WaT, 1024, 3072);
  transpose_cvt<<<dim3(1024/32, 1024/32), dim3(32, 8), 0, stream>>>(Wp, WpT, 1024, 1024);

  // 2) QKV GEMM -> qbuf / ktile / vtile
  gemm_kernel<0,128><<<dim3(24, 32), 256, 0, stream>>>(xb, WaT, ba, 3072, qbuf, ktile, vtile, nullptr);

  // 3) V suffix sums
  sufv_kernel<<<32, 256, 0, stream>>>(vtile, sufv);

  // 4) denominator pass (bf16 invD)
  dpass_kernel<<<1056, 256, 0, stream>>>(qbuf, ktile, invb);

  // 5) PV pass (4-wave one-barrier skeleton, static LDS)
  pv_kernel<<<1024, 256, 0, stream>>>(qbuf, ktile, vtile, invb, sufv, abuf, pbuf);

  // 6) reduce split partials
  reduce_kernel<<<512, 256, 0, stream>>>(pbuf, sufv, abuf);

  // 7) projection GEMM (BM=64 -> 512 blocks, 2/CU)
  gemm_kernel<1,64><<<dim3(1024/128, 4096/64), 256, 0, stream>>>(abuf, WpT, bp, 1024, nullptr, nullptr, nullptr, out);
}

// Round 12
// 164.612 us; speedup vs baseline: 1.3213x; 1.0970x over previous
//
#include <hip/hip_runtime.h>

#define DI __device__ __forceinline__

typedef __attribute__((ext_vector_type(8))) short s16x8;
typedef __attribute__((ext_vector_type(4))) short s16x4;
typedef __attribute__((ext_vector_type(4))) float f32x4;

DI unsigned short f2bf(float f){
  unsigned u = __float_as_uint(f);
  u = (u + 0x7FFFu + ((u >> 16) & 1u)) >> 16;
  return (unsigned short)u;
}
DI float bf2f(unsigned short h){
  return __uint_as_float(((unsigned)h) << 16);
}
DI float exp2i(float x){ float r; asm("v_exp_f32 %0, %1" : "=v"(r) : "v"(x)); return r; }

DI void gll16(const void* g, void* l){
  __builtin_amdgcn_global_load_lds((const __attribute__((address_space(1))) void*)g,
                                   (__attribute__((address_space(3))) void*)l, 16, 0, 0);
}

#define VMCNT(n) asm volatile("s_waitcnt vmcnt(" #n ")" ::: "memory")
#define SB() __builtin_amdgcn_sched_barrier(0)

// ---------------- elementwise fp32 -> bf16 ----------------
__global__ void cvt_kernel(const float* __restrict__ in, unsigned short* __restrict__ out, int n8){
  int i = blockIdx.x * blockDim.x + threadIdx.x;
  if (i >= n8) return;
  const float4* p = (const float4*)in + (size_t)i * 2;
  float4 a = p[0], b = p[1];
  s16x8 o;
  o[0] = (short)f2bf(a.x); o[1] = (short)f2bf(a.y); o[2] = (short)f2bf(a.z); o[3] = (short)f2bf(a.w);
  o[4] = (short)f2bf(b.x); o[5] = (short)f2bf(b.y); o[6] = (short)f2bf(b.z); o[7] = (short)f2bf(b.w);
  ((s16x8*)out)[i] = o;
}

// ---------------- transpose + convert: in fp32 [R][C] -> out bf16 [C][R] ----------------
__global__ void transpose_cvt(const float* __restrict__ in, unsigned short* __restrict__ out, int R, int C){
  __shared__ float t[32][33];
  int c0 = blockIdx.x * 32, r0 = blockIdx.y * 32;
  int tx = threadIdx.x, ty = threadIdx.y; // 32 x 8
  #pragma unroll
  for (int i = 0; i < 4; i++)
    t[ty + i*8][tx] = in[(size_t)(r0 + ty + i*8) * C + c0 + tx];
  __syncthreads();
  #pragma unroll
  for (int i = 0; i < 4; i++)
    out[(size_t)(c0 + ty + i*8) * R + r0 + tx] = f2bf(t[tx][ty + i*8]);
}

// ---------------- GEMM (m97 structure): C[M x N] = A[M x K] * Wt[N x K]^T + bias ----------------
// MODE 0 (BM=128): qkv -> qbuf rows (Q pre-scaled by log2e), ktile swz (direct),
//                  vtile swz via LDS-transposed coalesced stores.
// MODE 1 (BM=64): proj -> fp32 out.
template<int MODE, int BM>
__launch_bounds__(256)
__global__ void gemm_kernel(const unsigned short* __restrict__ A,
                            const unsigned short* __restrict__ Wt,
                            const float* __restrict__ bias,
                            int N,
                            unsigned short* __restrict__ qb,
                            unsigned short* __restrict__ kb,
                            unsigned short* __restrict__ vt,
                            float* __restrict__ out)
{
  constexpr int MI = BM / 32;
  constexpr int AC = BM / 32;
  const int K = 1024;
  __shared__ __align__(16) unsigned short Sm[BM*64 + 128*64];
  unsigned short* As = Sm;
  unsigned short* Bs = Sm + BM*64;
  int m0 = blockIdx.y * BM, n0 = blockIdx.x * 128;
  int tid = threadIdx.x;
  int lane = tid & 63, w = tid >> 6;
  int row_l = lane & 15, kgrp = lane >> 4;
  int wm = (w >> 1) * (MI * 16), wn = (w & 1) * 64;

  const unsigned short* asrc[AC];
  const unsigned short* bsrc[4];
  int ldsoA[AC], ldsoB[4];
  int chunk = (lane & 7) ^ (lane >> 3);
  #pragma unroll
  for (int c4 = 0; c4 < AC; c4++){
    int r = c4*32 + w*8 + (lane >> 3);
    asrc[c4] = A + (size_t)(m0 + r) * K + chunk*8;
    ldsoA[c4] = (c4*32 + w*8) * 64;
  }
  #pragma unroll
  for (int c4 = 0; c4 < 4; c4++){
    int r = c4*32 + w*8 + (lane >> 3);
    bsrc[c4] = Wt + (size_t)(n0 + r) * K + chunk*8;
    ldsoB[c4] = (c4*32 + w*8) * 64;
  }
  int eA[MI], eB[4];
  #pragma unroll
  for (int i = 0; i < MI; i++){
    int ra = wm + i*16 + row_l;
    eA[i] = (ra*64 + kgrp*8) ^ ((ra & 7) << 3);
  }
  #pragma unroll
  for (int i = 0; i < 4; i++){
    int rb = wn + i*16 + row_l;
    eB[i] = (rb*64 + kgrp*8) ^ ((rb & 7) << 3);
  }

  f32x4 acc[MI][4];
  #pragma unroll
  for (int i = 0; i < MI; i++)
    #pragma unroll
    for (int j = 0; j < 4; j++)
      acc[i][j] = (f32x4){0.f, 0.f, 0.f, 0.f};

  for (int k0 = 0; k0 < K; k0 += 64){
    #pragma unroll
    for (int c4 = 0; c4 < AC; c4++)
      gll16(asrc[c4] + k0, (void*)(As + ldsoA[c4]));
    #pragma unroll
    for (int c4 = 0; c4 < 4; c4++)
      gll16(bsrc[c4] + k0, (void*)(Bs + ldsoB[c4]));
    __syncthreads();
    #pragma unroll
    for (int kc = 0; kc < 2; kc++){
      s16x8 af[MI], bfr[4];
      #pragma unroll
      for (int mi = 0; mi < MI; mi++)
        af[mi] = *(const s16x8*)&As[eA[mi] ^ (kc*32)];
      #pragma unroll
      for (int ni = 0; ni < 4; ni++)
        bfr[ni] = *(const s16x8*)&Bs[eB[ni] ^ (kc*32)];
      #pragma unroll
      for (int mi = 0; mi < MI; mi++)
        #pragma unroll
        for (int ni = 0; ni < 4; ni++)
          acc[mi][ni] = __builtin_amdgcn_mfma_f32_16x16x32_bf16(af[mi], bfr[ni], acc[mi][ni], 0, 0, 0);
    }
    __syncthreads();
  }

  if (MODE == 0){
    // --- q/k direct stores + V columns into transposed LDS tile (u64 units, mq-XOR swz) ---
    unsigned long long* ldsT = (unsigned long long*)Sm;   // [np 0..127][mq 0..31] u64
    #pragma unroll
    for (int mi = 0; mi < MI; mi++){
      #pragma unroll
      for (int ni = 0; ni < 4; ni++){
        int np = wn + ni*16 + row_l;
        int gc = n0 + np;
        int hh = gc / 192, cc = gc % 192;
        float bia = bias[gc];
        if (cc < 128){
          #pragma unroll
          for (int j = 0; j < 4; j++){
            int gr = m0 + wm + mi*16 + kgrp*4 + j;
            float v = acc[mi][ni][j] + bia;
            if (cc < 64){
              qb[(size_t)gr * 1024 + hh*64 + cc] = f2bf(v * 1.44269504f);
            } else {
              int d = cc - 64; int b = gr >> 11, s = gr & 2047;
              int kt = s >> 6, kk = s & 63;
              kb[(size_t)((b*16 + hh)*32 + kt) * 4096 + ((kk*64 + d) ^ ((kk & 7) << 3))] = f2bf(v);
            }
          }
        } else {
          float v0 = acc[mi][ni][0] + bia, v1 = acc[mi][ni][1] + bia;
          float v2 = acc[mi][ni][2] + bia, v3 = acc[mi][ni][3] + bia;
          unsigned lo, hi;
          asm("v_cvt_pk_bf16_f32 %0, %1, %2" : "=v"(lo) : "v"(v0), "v"(v1));
          asm("v_cvt_pk_bf16_f32 %0, %1, %2" : "=v"(hi) : "v"(v2), "v"(v3));
          int mq = (wm + mi*16 + kgrp*4) >> 2;
          ldsT[np*32 + (mq ^ ((np & 7) << 2))] = ((unsigned long long)hi << 32) | (unsigned long long)lo;
        }
      }
    }
    __syncthreads();
    int bb = m0 >> 11, s_base = m0 & 2047;
    for (int item = tid; item < 2048; item += 256){
      int np = item >> 4;
      int gcv = n0 + np;
      int cc = gcv % 192;
      if (cc < 128) continue;
      int d = cc - 128, hh = gcv / 192;
      int sub = (item >> 3) & 1;
      int c = item & 7;
      int mq0 = sub*16 + c*2;
      s16x8 val = *(const s16x8*)&Sm[np*128 + ((mq0 ^ ((np & 7) << 2)) << 2)];
      size_t base = ((size_t)((bb*16 + hh)*32) + (s_base >> 6) + sub) * 4096 + d*64 + ((c ^ (d & 7)) << 3);
      *(s16x8*)&vt[base] = val;
    }
  } else {
    #pragma unroll
    for (int mi = 0; mi < MI; mi++){
      #pragma unroll
      for (int ni = 0; ni < 4; ni++){
        #pragma unroll
        for (int j = 0; j < 4; j++){
          int gr = m0 + wm + mi*16 + kgrp*4 + j;
          int gc = n0 + wn + ni*16 + row_l;
          out[(size_t)gr * N + gc] = acc[mi][ni][j] + bias[gc];
        }
      }
    }
  }
}

// ---------------- V suffix sums (64-key granularity): sufv[bh][t in 0..32][64d] ----------------
__global__ void sufv_kernel(const unsigned short* __restrict__ vt, float* __restrict__ sufv){
  __shared__ float tot[4][64];
  int bh = blockIdx.x;                 // 32
  int tid = threadIdx.x;               // 256
  int tq = tid >> 6, d = tid & 63;
  const unsigned short* base = vt + (size_t)bh * 32 * 4096;
  float s[8];
  float run = 0.f;
  for (int j = 7; j >= 0; j--){
    int t = tq*8 + j;
    float rs = 0.f;
    #pragma unroll
    for (int c = 0; c < 8; c++){
      int idx = (d*64 + c*8) ^ ((d & 7) << 3);
      s16x8 v = *(const s16x8*)&base[(size_t)t*4096 + idx];
      #pragma unroll
      for (int e = 0; e < 8; e++) rs += bf2f((unsigned short)v[e]);
    }
    run += rs; s[j] = run;
  }
  tot[tq][d] = run;
  __syncthreads();
  float carry = 0.f;
  for (int t2 = tq+1; t2 < 4; t2++) carry += tot[t2][d];
  #pragma unroll
  for (int j = 0; j < 8; j++)
    sufv[((size_t)bh*33 + tq*8 + j)*64 + d] = s[j] + carry;
  if (tid < 64) sufv[((size_t)bh*33 + 32)*64 + tid] = 0.f;
}

// ---------------- D-pass: invb[b][q][k] (bf16) = 1 / sum_h exp(s_h(q,k)) over causal triangle ----------------
__launch_bounds__(256)
__global__ void dpass_kernel(const unsigned short* __restrict__ qbuf,
                             const unsigned short* __restrict__ kb,
                             unsigned short* __restrict__ invb)
{
  __shared__ unsigned short Kst[4][4096];
  int bid = blockIdx.x;                       // 1056 = 8 * 132
  int blk = (bid & 7) * 132 + (bid >> 3);     // XCD swizzle (bijective)
  int b = blk / 528, t = blk % 528;
  int kt = (int)(32.5f - sqrtf(1056.25f - 2.f*t));
  while (kt*(65-kt)/2 > t) kt--;
  while ((kt+1)*(64-kt)/2 <= t) kt++;
  int qt = kt + (t - kt*(65-kt)/2);

  int tid = threadIdx.x, lane = tid & 63, w = tid >> 6;
  int row_l = lane & 15, kgrp = lane >> 4;

  const unsigned short* ktb = kb + ((size_t)(b*16)*32 + kt) * 4096;
  int sgoff = (w*128 + lane)*8;

  auto stage = [&](int hh, int buf){
    const unsigned short* src = ktb + (size_t)hh * 131072;
    gll16(src + sgoff,       (void*)(&Kst[buf][0] + w*1024));
    gll16(src + sgoff + 512, (void*)(&Kst[buf][0] + w*1024 + 512));
  };

  int e0[4];
  #pragma unroll
  for (int ks = 0; ks < 4; ks++){
    int row = ks*16 + row_l;
    e0[ks] = (row*64 + kgrp*8) ^ ((row & 7) << 3);
  }

  stage(0, 0);
  stage(1, 1);

  f32x4 esum[4];
  #pragma unroll
  for (int ks = 0; ks < 4; ks++) esum[ks] = (f32x4){0.f,0.f,0.f,0.f};

  const unsigned short* qrow_p = qbuf + (size_t)(b*2048 + qt*64 + w*16 + row_l) * 1024;
  s16x8 qf0 = *(const s16x8*)&qrow_p[kgrp*8];
  s16x8 qf1 = *(const s16x8*)&qrow_p[32 + kgrp*8];

  for (int h = 0; h < 16; h++){
    s16x8 qn0, qn1;
    if (h < 15){
      qn0 = *(const s16x8*)&qrow_p[(h+1)*64 + kgrp*8];
      qn1 = *(const s16x8*)&qrow_p[(h+1)*64 + 32 + kgrp*8];
    }
    if (h + 2 < 16) stage(h+2, (h+2) & 3);
    SB();
    if (h < 14)      VMCNT(8);
    else if (h < 15) VMCNT(6);
    else             VMCNT(2);
    SB();
    __builtin_amdgcn_s_barrier();
    SB();

    const unsigned short* kl = &Kst[h & 3][0];
    #pragma unroll
    for (int ks = 0; ks < 4; ks++){
      s16x8 a0 = *(const s16x8*)&kl[e0[ks]];
      s16x8 a1 = *(const s16x8*)&kl[e0[ks] ^ 32];
      f32x4 sc = __builtin_amdgcn_mfma_f32_16x16x32_bf16(a0, qf0, (f32x4){0.f,0.f,0.f,0.f}, 0, 0, 0);
      sc = __builtin_amdgcn_mfma_f32_16x16x32_bf16(a1, qf1, sc, 0, 0, 0);
      #pragma unroll
      for (int j = 0; j < 4; j++) esum[ks][j] += exp2i(sc[j]);
    }
    if (h < 15){ qf0 = qn0; qf1 = qn1; }
  }

  int qcol = qt*64 + w*16 + row_l;
  unsigned short* dst = invb + (size_t)b*4194304 + (size_t)qcol*2048 + kt*64 + kgrp*4;
  #pragma unroll
  for (int ks = 0; ks < 4; ks++){
    float r0 = 1.f/esum[ks][0], r1 = 1.f/esum[ks][1];
    float r2 = 1.f/esum[ks][2], r3 = 1.f/esum[ks][3];
    unsigned lo, hi;
    asm("v_cvt_pk_bf16_f32 %0, %1, %2" : "=v"(lo) : "v"(r0), "v"(r1));
    asm("v_cvt_pk_bf16_f32 %0, %1, %2" : "=v"(hi) : "v"(r2), "v"(r3));
    uint2 pk; pk.x = lo; pk.y = hi;
    *(uint2*)&dst[ks*16] = pk;
  }
}

// ---------------- PV-pass v8: uniform pair blocks + R10-PROVEN sync skeleton ----------------
// grid 512 = (b, h, pair i) XCD-swizzled; block runs q-tile i (i+1 k-tiles) then q-tile 31-i
// (32-i k-tiles) = exactly 33 tiles; 2 blocks/CU, all stores direct (no partials/reduce).
// K ring-4 staged PRE-barrier at kt+2 (safe: overwrites buffer last read 2 barriers ago);
// V ring-2 staged POST-barrier at kt+1 (safe). 57.75 KB static LDS.
// VMCNT counts (ops newer than stageV(kt)): first iter 12/10/4; steady 6/4/0. (R10-verified.)
__launch_bounds__(256)
__global__ void pv_kernel(const unsigned short* __restrict__ qbuf,
                          const unsigned short* __restrict__ kb,
                          const unsigned short* __restrict__ vt,
                          const unsigned short* __restrict__ invb,
                          const float* __restrict__ sufv,
                          unsigned short* __restrict__ ab)
{
  __shared__ unsigned short Kst[4][4096];   // 32 KB
  __shared__ unsigned short Vst[2][4096];   // 16 KB
  __shared__ unsigned short Wsh[4][1152];   // 9 KB (per-wave private)

  int bid = blockIdx.x;                      // 512 = 8 * 64
  int blk = ((bid & 7) << 6) | (bid >> 3);   // XCD swizzle (bijective)
  int i = blk & 15;
  int h = (blk >> 4) & 15;
  int b = blk >> 8;

  int tid = threadIdx.x, lane = tid & 63, w = tid >> 6;
  int row_l = lane & 15, kgrp = lane >> 4;

  const unsigned short* KT = kb + (size_t)((b*16 + h)*32) * 4096;
  const unsigned short* VT = vt + (size_t)((b*16 + h)*32) * 4096;
  int sgoff = (w*128 + lane)*8;
  unsigned short* Wsw = &Wsh[w][0];

  int eK[4];
  #pragma unroll
  for (int ks = 0; ks < 4; ks++){
    int row = ks*16 + row_l;
    eK[ks] = (row*64 + kgrp*8) ^ ((row & 7) << 3);
  }

  auto stageK = [&](int kt, int buf){
    gll16(KT + (size_t)kt*4096 + sgoff,       (void*)(&Kst[buf][0] + w*1024));
    gll16(KT + (size_t)kt*4096 + sgoff + 512, (void*)(&Kst[buf][0] + w*1024 + 512));
  };
  auto stageV = [&](int kt, int buf){
    gll16(VT + (size_t)kt*4096 + sgoff,       (void*)(&Vst[buf][0] + w*1024));
    gll16(VT + (size_t)kt*4096 + sgoff + 512, (void*)(&Vst[buf][0] + w*1024 + 512));
  };

  auto run = [&](int qt, int k1t){            // k-range [0, k1t)
    int q0 = qt * 64;
    int qv = q0 + w*16 + row_l;
    const unsigned short* qrow_p = qbuf + (size_t)(b*2048 + qv) * 1024 + h*64;
    s16x8 qf0 = *(const s16x8*)&qrow_p[kgrp*8];
    s16x8 qf1 = *(const s16x8*)&qrow_p[32 + kgrp*8];
    SB();                                     // pin qf loads before the counted region
    const unsigned short* ivrow = invb + (size_t)b*4194304 + (size_t)qv*2048 + kgrp*4;

    f32x4 pvv[4];
    #pragma unroll
    for (int d = 0; d < 4; d++) pvv[d] = (f32x4){0.f,0.f,0.f,0.f};

    __syncthreads();                          // all waves done with previous segment's buffers
    // prologue: K(0)[2], V(0)[2], inv(0)[4], K(1)[2]
    stageK(0, 0);
    stageV(0, 0);
    s16x4 i1[4];
    #pragma unroll
    for (int ks = 0; ks < 4; ks++) i1[ks] = *(const s16x4*)&ivrow[ks*16];
    if (1 < k1t) stageK(1, 1);
    SB();

    for (int kt = 0; kt < k1t; kt++){
      bool nx1 = (kt + 1 < k1t), nx2 = (kt + 2 < k1t);
      bool first = (kt == 0);

      s16x4 icur[4];
      #pragma unroll
      for (int ks = 0; ks < 4; ks++) icur[ks] = i1[ks];
      if (nx1){
        #pragma unroll
        for (int ks = 0; ks < 4; ks++) i1[ks] = *(const s16x4*)&ivrow[(kt+1)*64 + ks*16];  // 4 vm
      }
      SB();
      if (nx2) stageK(kt+2, (kt+2) & 3);      // 2 vm; overwrites buffer read 2 barriers ago: SAFE
      SB();
      // wait: stageK(kt) and stageV(kt) retired (audited newer-op counts)
      if (first){
        if (nx2)      VMCNT(12);
        else if (nx1) VMCNT(10);
        else          VMCNT(4);
      } else {
        if (nx2)      VMCNT(6);
        else if (nx1) VMCNT(4);
        else          VMCNT(0);
      }
      SB();
      __builtin_amdgcn_s_barrier();           // publish K(kt), V(kt)
      SB();
      if (nx1) stageV(kt+1, (kt+1) & 1);      // post-barrier: V(kt-1) overwrite safe
      SB();

      const unsigned short* kl = &Kst[kt & 3][0];
      const unsigned short* vl = &Vst[kt & 1][0];
      // QK^T (swapped: rows=key, cols=q); Q pre-scaled by log2e
      f32x4 sc[4];
      #pragma unroll
      for (int ks = 0; ks < 4; ks++){
        s16x8 a0 = *(const s16x8*)&kl[eK[ks]];
        s16x8 a1 = *(const s16x8*)&kl[eK[ks] ^ 32];
        sc[ks] = __builtin_amdgcn_mfma_f32_16x16x32_bf16(a0, qf0, (f32x4){0.f,0.f,0.f,0.f}, 0, 0, 0);
        sc[ks] = __builtin_amdgcn_mfma_f32_16x16x32_bf16(a1, qf1, sc[ks], 0, 0, 0);
      }

      // weights: w = exp2(s') * invD (masked -> exactly 1/16, diagonal tile only)
      if (kt == qt){
        int kbase = kt*64 + kgrp*4;
        #pragma unroll
        for (int ks = 0; ks < 4; ks++){
          #pragma unroll
          for (int j = 0; j < 4; j++){
            float wv = exp2i(sc[ks][j]) * bf2f((unsigned short)icur[ks][j]);
            sc[ks][j] = (kbase + ks*16 + j > qv) ? 0.0625f : wv;
          }
          unsigned lo, hi;
          asm("v_cvt_pk_bf16_f32 %0, %1, %2" : "=v"(lo) : "v"(sc[ks][0]), "v"(sc[ks][1]));
          asm("v_cvt_pk_bf16_f32 %0, %1, %2" : "=v"(hi) : "v"(sc[ks][2]), "v"(sc[ks][3]));
          uint2 pk2; pk2.x = lo; pk2.y = hi;
          *(uint2*)&Wsw[row_l*72 + ks*16 + kgrp*4] = pk2;
        }
      } else {
        #pragma unroll
        for (int ks = 0; ks < 4; ks++){
          #pragma unroll
          for (int j = 0; j < 4; j++)
            sc[ks][j] = exp2i(sc[ks][j]) * bf2f((unsigned short)icur[ks][j]);
          unsigned lo, hi;
          asm("v_cvt_pk_bf16_f32 %0, %1, %2" : "=v"(lo) : "v"(sc[ks][0]), "v"(sc[ks][1]));
          asm("v_cvt_pk_bf16_f32 %0, %1, %2" : "=v"(hi) : "v"(sc[ks][2]), "v"(sc[ks][3]));
          uint2 pk2; pk2.x = lo; pk2.y = hi;
          *(uint2*)&Wsw[row_l*72 + ks*16 + kgrp*4] = pk2;
        }
      }

      // PV (per-wave private Ws: same-wave lgkm ordering, no barrier)
      #pragma unroll
      for (int kc = 0; kc < 2; kc++){
        s16x8 af = *(const s16x8*)&Wsw[row_l*72 + kc*32 + kgrp*8];
        #pragma unroll
        for (int dq = 0; dq < 4; dq++){
          s16x8 vf = *(const s16x8*)&vl[eK[dq] ^ (kc*32)];
          pvv[dq] = __builtin_amdgcn_mfma_f32_16x16x32_bf16(af, vf, pvv[dq], 0, 0, 0);
        }
      }
    }

    // epilogue (direct): rows q = q0 + w*16 + kgrp*4 + j; cols d = dq*16 + row_l
    int tsuf = qt + 1;
    #pragma unroll
    for (int dq = 0; dq < 4; dq++){
      int d = dq*16 + row_l;
      float suf = sufv[((size_t)(b*16 + h)*33 + tsuf)*64 + d];
      #pragma unroll
      for (int j = 0; j < 4; j++){
        int qo = q0 + w*16 + kgrp*4 + j;
        ab[(size_t)(b*2048 + qo)*1024 + h*64 + d] = f2bf(pvv[dq][j] + 0.0625f * suf);
      }
    }
  };

  run(i, i + 1);
  run(31 - i, 32 - i);
}

// ---------------- host ----------------
extern "C" void kernel_launch(void* const* d_in, const int* in_sizes, int n_in,
                              void* d_out, int out_size, void* d_ws, size_t ws_size,
                              hipStream_t stream) {
  (void)in_sizes; (void)n_in; (void)out_size; (void)ws_size;
  const float* x  = (const float*)d_in[0];
  const float* Wa = (const float*)d_in[1];
  const float* ba = (const float*)d_in[2];
  const float* Wp = (const float*)d_in[3];
  const float* bp = (const float*)d_in[4];
  float* out = (float*)d_out;

  char* ws = (char*)d_ws;
  size_t off = 0;
  auto alloc = [&](size_t bytes) -> void* {
    void* p = ws + off;
    off += (bytes + 255) & ~(size_t)255;
    return p;
  };
  unsigned short* xb   = (unsigned short*)alloc((size_t)4096*1024*2);
  unsigned short* WaT  = (unsigned short*)alloc((size_t)3072*1024*2);
  unsigned short* WpT  = (unsigned short*)alloc((size_t)1024*1024*2);
  unsigned short* qbuf = (unsigned short*)alloc((size_t)4096*1024*2);
  unsigned short* ktile= (unsigned short*)alloc((size_t)4096*1024*2);
  unsigned short* vtile= (unsigned short*)alloc((size_t)4096*1024*2);
  unsigned short* abuf = (unsigned short*)alloc((size_t)4096*1024*2);
  unsigned short* invb = (unsigned short*)alloc((size_t)2*2048*2048*2); // bf16 invD
  float* sufv          = (float*)alloc((size_t)32*33*64*4);

  // 1) conversions
  cvt_kernel<<<2048, 256, 0, stream>>>(x, xb, 4096*1024/8);
  transpose_cvt<<<dim3(3072/32, 1024/32), dim3(32, 8), 0, stream>>>(Wa, WaT, 1024, 3072);
  transpose_cvt<<<dim3(1024/32, 1024/32), dim3(32, 8), 0, stream>>>(Wp, WpT, 1024, 1024);

  // 2) QKV GEMM -> qbuf / ktile / vtile (V via LDS-transposed coalesced stores)
  gemm_kernel<0,128><<<dim3(24, 32), 256, 0, stream>>>(xb, WaT, ba, 3072, qbuf, ktile, vtile, nullptr);

  // 3) V suffix sums
  sufv_kernel<<<32, 256, 0, stream>>>(vtile, sufv);

  // 4) denominator pass (bf16 invD)
  dpass_kernel<<<1056, 256, 0, stream>>>(qbuf, ktile, invb);

  // 5) PV pass (uniform pair blocks, R10-proven rings, direct stores)
  pv_kernel<<<512, 256, 0, stream>>>(qbuf, ktile, vtile, invb, sufv, abuf);

  // 6) projection GEMM (BM=64 -> 512 blocks, 2/CU)
  gemm_kernel<1,64><<<dim3(1024/128, 4096/64), 256, 0, stream>>>(abuf, WpT, bp, 1024, nullptr, nullptr, nullptr, out);
}

// Round 13
// 158.238 us; speedup vs baseline: 1.3746x; 1.0403x over previous
//
#include <hip/hip_runtime.h>

#define DI __device__ __forceinline__

typedef __attribute__((ext_vector_type(8))) short s16x8;
typedef __attribute__((ext_vector_type(4))) short s16x4;
typedef __attribute__((ext_vector_type(4))) float f32x4;

DI unsigned short f2bf(float f){
  unsigned u = __float_as_uint(f);
  u = (u + 0x7FFFu + ((u >> 16) & 1u)) >> 16;
  return (unsigned short)u;
}
DI float bf2f(unsigned short h){
  return __uint_as_float(((unsigned)h) << 16);
}
DI float exp2i(float x){ float r; asm("v_exp_f32 %0, %1" : "=v"(r) : "v"(x)); return r; }

DI void gll16(const void* g, void* l){
  __builtin_amdgcn_global_load_lds((const __attribute__((address_space(1))) void*)g,
                                   (__attribute__((address_space(3))) void*)l, 16, 0, 0);
}

#define VMCNT(n) asm volatile("s_waitcnt vmcnt(" #n ")" ::: "memory")
#define SB() __builtin_amdgcn_sched_barrier(0)

// ---------------- elementwise fp32 -> bf16 ----------------
__global__ void cvt_kernel(const float* __restrict__ in, unsigned short* __restrict__ out, int n8){
  int i = blockIdx.x * blockDim.x + threadIdx.x;
  if (i >= n8) return;
  const float4* p = (const float4*)in + (size_t)i * 2;
  float4 a = p[0], b = p[1];
  s16x8 o;
  o[0] = (short)f2bf(a.x); o[1] = (short)f2bf(a.y); o[2] = (short)f2bf(a.z); o[3] = (short)f2bf(a.w);
  o[4] = (short)f2bf(b.x); o[5] = (short)f2bf(b.y); o[6] = (short)f2bf(b.z); o[7] = (short)f2bf(b.w);
  ((s16x8*)out)[i] = o;
}

// ---------------- transpose + convert: in fp32 [R][C] -> out bf16 [C][R] ----------------
__global__ void transpose_cvt(const float* __restrict__ in, unsigned short* __restrict__ out, int R, int C){
  __shared__ float t[32][33];
  int c0 = blockIdx.x * 32, r0 = blockIdx.y * 32;
  int tx = threadIdx.x, ty = threadIdx.y; // 32 x 8
  #pragma unroll
  for (int i = 0; i < 4; i++)
    t[ty + i*8][tx] = in[(size_t)(r0 + ty + i*8) * C + c0 + tx];
  __syncthreads();
  #pragma unroll
  for (int i = 0; i < 4; i++)
    out[(size_t)(c0 + ty + i*8) * R + r0 + tx] = f2bf(t[tx][ty + i*8]);
}

// ---------------- GEMM (m97 structure): C[M x N] = A[M x K] * Wt[N x K]^T + bias ----------------
// MODE 0 (BM=128): qkv -> qbuf rows (Q pre-scaled by log2e), ktile swz (direct),
//                  vtile swz via LDS-transposed coalesced stores.
// MODE 1 (BM=64): proj -> fp32 out.
// Both: XCD-contiguous block swizzle (nwg % 8 == 0).
template<int MODE, int BM>
__launch_bounds__(256)
__global__ void gemm_kernel(const unsigned short* __restrict__ A,
                            const unsigned short* __restrict__ Wt,
                            const float* __restrict__ bias,
                            int N,
                            unsigned short* __restrict__ qb,
                            unsigned short* __restrict__ kb,
                            unsigned short* __restrict__ vt,
                            float* __restrict__ out)
{
  constexpr int MI = BM / 32;
  constexpr int AC = BM / 32;
  const int K = 1024;
  __shared__ __align__(16) unsigned short Sm[BM*64 + 128*64];
  unsigned short* As = Sm;
  unsigned short* Bs = Sm + BM*64;

  // XCD-contiguous swizzle on the linear block id
  int lin = blockIdx.y * gridDim.x + blockIdx.x;
  int chunk = (gridDim.x * gridDim.y) >> 3;
  int v = (lin & 7) * chunk + (lin >> 3);
  int bx = v % gridDim.x, by = v / gridDim.x;
  int m0 = by * BM, n0 = bx * 128;

  int tid = threadIdx.x;
  int lane = tid & 63, w = tid >> 6;
  int row_l = lane & 15, kgrp = lane >> 4;
  int wm = (w >> 1) * (MI * 16), wn = (w & 1) * 64;

  const unsigned short* asrc[AC];
  const unsigned short* bsrc[4];
  int ldsoA[AC], ldsoB[4];
  int chnk = (lane & 7) ^ (lane >> 3);
  #pragma unroll
  for (int c4 = 0; c4 < AC; c4++){
    int r = c4*32 + w*8 + (lane >> 3);
    asrc[c4] = A + (size_t)(m0 + r) * K + chnk*8;
    ldsoA[c4] = (c4*32 + w*8) * 64;
  }
  #pragma unroll
  for (int c4 = 0; c4 < 4; c4++){
    int r = c4*32 + w*8 + (lane >> 3);
    bsrc[c4] = Wt + (size_t)(n0 + r) * K + chnk*8;
    ldsoB[c4] = (c4*32 + w*8) * 64;
  }
  int eA[MI], eB[4];
  #pragma unroll
  for (int i = 0; i < MI; i++){
    int ra = wm + i*16 + row_l;
    eA[i] = (ra*64 + kgrp*8) ^ ((ra & 7) << 3);
  }
  #pragma unroll
  for (int i = 0; i < 4; i++){
    int rb = wn + i*16 + row_l;
    eB[i] = (rb*64 + kgrp*8) ^ ((rb & 7) << 3);
  }

  f32x4 acc[MI][4];
  #pragma unroll
  for (int i = 0; i < MI; i++)
    #pragma unroll
    for (int j = 0; j < 4; j++)
      acc[i][j] = (f32x4){0.f, 0.f, 0.f, 0.f};

  for (int k0 = 0; k0 < K; k0 += 64){
    #pragma unroll
    for (int c4 = 0; c4 < AC; c4++)
      gll16(asrc[c4] + k0, (void*)(As + ldsoA[c4]));
    #pragma unroll
    for (int c4 = 0; c4 < 4; c4++)
      gll16(bsrc[c4] + k0, (void*)(Bs + ldsoB[c4]));
    __syncthreads();
    #pragma unroll
    for (int kc = 0; kc < 2; kc++){
      s16x8 af[MI], bfr[4];
      #pragma unroll
      for (int mi = 0; mi < MI; mi++)
        af[mi] = *(const s16x8*)&As[eA[mi] ^ (kc*32)];
      #pragma unroll
      for (int ni = 0; ni < 4; ni++)
        bfr[ni] = *(const s16x8*)&Bs[eB[ni] ^ (kc*32)];
      #pragma unroll
      for (int mi = 0; mi < MI; mi++)
        #pragma unroll
        for (int ni = 0; ni < 4; ni++)
          acc[mi][ni] = __builtin_amdgcn_mfma_f32_16x16x32_bf16(af[mi], bfr[ni], acc[mi][ni], 0, 0, 0);
    }
    __syncthreads();
  }

  if (MODE == 0){
    // --- q/k direct stores + V columns into transposed LDS tile (u64 units, mq-XOR swz) ---
    unsigned long long* ldsT = (unsigned long long*)Sm;   // [np 0..127][mq 0..31] u64
    #pragma unroll
    for (int mi = 0; mi < MI; mi++){
      #pragma unroll
      for (int ni = 0; ni < 4; ni++){
        int np = wn + ni*16 + row_l;
        int gc = n0 + np;
        int hh = gc / 192, cc = gc % 192;
        float bia = bias[gc];
        if (cc < 128){
          #pragma unroll
          for (int j = 0; j < 4; j++){
            int gr = m0 + wm + mi*16 + kgrp*4 + j;
            float v2 = acc[mi][ni][j] + bia;
            if (cc < 64){
              qb[(size_t)gr * 1024 + hh*64 + cc] = f2bf(v2 * 1.44269504f);
            } else {
              int d = cc - 64; int b = gr >> 11, s = gr & 2047;
              int kt = s >> 6, kk = s & 63;
              kb[(size_t)((b*16 + hh)*32 + kt) * 4096 + ((kk*64 + d) ^ ((kk & 7) << 3))] = f2bf(v2);
            }
          }
        } else {
          float v0 = acc[mi][ni][0] + bia, v1 = acc[mi][ni][1] + bia;
          float v2 = acc[mi][ni][2] + bia, v3 = acc[mi][ni][3] + bia;
          unsigned lo, hi;
          asm("v_cvt_pk_bf16_f32 %0, %1, %2" : "=v"(lo) : "v"(v0), "v"(v1));
          asm("v_cvt_pk_bf16_f32 %0, %1, %2" : "=v"(hi) : "v"(v2), "v"(v3));
          int mq = (wm + mi*16 + kgrp*4) >> 2;
          ldsT[np*32 + (mq ^ ((np & 7) << 2))] = ((unsigned long long)hi << 32) | (unsigned long long)lo;
        }
      }
    }
    __syncthreads();
    int bb = m0 >> 11, s_base = m0 & 2047;
    for (int item = tid; item < 2048; item += 256){
      int np = item >> 4;
      int gcv = n0 + np;
      int cc = gcv % 192;
      if (cc < 128) continue;
      int d = cc - 128, hh = gcv / 192;
      int sub = (item >> 3) & 1;
      int c = item & 7;
      int mq0 = sub*16 + c*2;
      s16x8 val = *(const s16x8*)&Sm[np*128 + ((mq0 ^ ((np & 7) << 2)) << 2)];
      size_t base = ((size_t)((bb*16 + hh)*32) + (s_base >> 6) + sub) * 4096 + d*64 + ((c ^ (d & 7)) << 3);
      *(s16x8*)&vt[base] = val;
    }
  } else {
    #pragma unroll
    for (int mi = 0; mi < MI; mi++){
      #pragma unroll
      for (int ni = 0; ni < 4; ni++){
        #pragma unroll
        for (int j = 0; j < 4; j++){
          int gr = m0 + wm + mi*16 + kgrp*4 + j;
          int gc = n0 + wn + ni*16 + row_l;
          out[(size_t)gr * N + gc] = acc[mi][ni][j] + bias[gc];
        }
      }
    }
  }
}

// ---------------- V suffix sums (64-key granularity): sufv[bh][t in 0..32][64d] ----------------
__global__ void sufv_kernel(const unsigned short* __restrict__ vt, float* __restrict__ sufv){
  __shared__ float tot[4][64];
  int bh = blockIdx.x;                 // 32
  int tid = threadIdx.x;               // 256
  int tq = tid >> 6, d = tid & 63;
  const unsigned short* base = vt + (size_t)bh * 32 * 4096;
  float s[8];
  float run = 0.f;
  for (int j = 7; j >= 0; j--){
    int t = tq*8 + j;
    float rs = 0.f;
    #pragma unroll
    for (int c = 0; c < 8; c++){
      int idx = (d*64 + c*8) ^ ((d & 7) << 3);
      s16x8 v = *(const s16x8*)&base[(size_t)t*4096 + idx];
      #pragma unroll
      for (int e = 0; e < 8; e++) rs += bf2f((unsigned short)v[e]);
    }
    run += rs; s[j] = run;
  }
  tot[tq][d] = run;
  __syncthreads();
  float carry = 0.f;
  for (int t2 = tq+1; t2 < 4; t2++) carry += tot[t2][d];
  #pragma unroll
  for (int j = 0; j < 8; j++)
    sufv[((size_t)bh*33 + tq*8 + j)*64 + d] = s[j] + carry;
  if (tid < 64) sufv[((size_t)bh*33 + 32)*64 + tid] = 0.f;
}

// ---------------- D-pass: invb[b][q][k] (bf16) = 1 / sum_h exp(s_h(q,k)) over causal triangle ----------------
__launch_bounds__(256)
__global__ void dpass_kernel(const unsigned short* __restrict__ qbuf,
                             const unsigned short* __restrict__ kb,
                             unsigned short* __restrict__ invb)
{
  __shared__ unsigned short Kst[4][4096];
  int bid = blockIdx.x;                       // 1056 = 8 * 132
  int blk = (bid & 7) * 132 + (bid >> 3);     // XCD swizzle (bijective)
  int b = blk / 528, t = blk % 528;
  int kt = (int)(32.5f - sqrtf(1056.25f - 2.f*t));
  while (kt*(65-kt)/2 > t) kt--;
  while ((kt+1)*(64-kt)/2 <= t) kt++;
  int qt = kt + (t - kt*(65-kt)/2);

  int tid = threadIdx.x, lane = tid & 63, w = tid >> 6;
  int row_l = lane & 15, kgrp = lane >> 4;

  const unsigned short* ktb = kb + ((size_t)(b*16)*32 + kt) * 4096;
  int sgoff = (w*128 + lane)*8;

  auto stage = [&](int hh, int buf){
    const unsigned short* src = ktb + (size_t)hh * 131072;
    gll16(src + sgoff,       (void*)(&Kst[buf][0] + w*1024));
    gll16(src + sgoff + 512, (void*)(&Kst[buf][0] + w*1024 + 512));
  };

  int e0[4];
  #pragma unroll
  for (int ks = 0; ks < 4; ks++){
    int row = ks*16 + row_l;
    e0[ks] = (row*64 + kgrp*8) ^ ((row & 7) << 3);
  }

  stage(0, 0);
  stage(1, 1);

  f32x4 esum[4];
  #pragma unroll
  for (int ks = 0; ks < 4; ks++) esum[ks] = (f32x4){0.f,0.f,0.f,0.f};

  const unsigned short* qrow_p = qbuf + (size_t)(b*2048 + qt*64 + w*16 + row_l) * 1024;
  s16x8 qf0 = *(const s16x8*)&qrow_p[kgrp*8];
  s16x8 qf1 = *(const s16x8*)&qrow_p[32 + kgrp*8];

  for (int h = 0; h < 16; h++){
    s16x8 qn0, qn1;
    if (h < 15){
      qn0 = *(const s16x8*)&qrow_p[(h+1)*64 + kgrp*8];
      qn1 = *(const s16x8*)&qrow_p[(h+1)*64 + 32 + kgrp*8];
    }
    if (h + 2 < 16) stage(h+2, (h+2) & 3);
    SB();
    if (h < 14)      VMCNT(8);
    else if (h < 15) VMCNT(6);
    else             VMCNT(2);
    SB();
    __builtin_amdgcn_s_barrier();
    SB();

    const unsigned short* kl = &Kst[h & 3][0];
    #pragma unroll
    for (int ks = 0; ks < 4; ks++){
      s16x8 a0 = *(const s16x8*)&kl[e0[ks]];
      s16x8 a1 = *(const s16x8*)&kl[e0[ks] ^ 32];
      f32x4 sc = __builtin_amdgcn_mfma_f32_16x16x32_bf16(a0, qf0, (f32x4){0.f,0.f,0.f,0.f}, 0, 0, 0);
      sc = __builtin_amdgcn_mfma_f32_16x16x32_bf16(a1, qf1, sc, 0, 0, 0);
      #pragma unroll
      for (int j = 0; j < 4; j++) esum[ks][j] += exp2i(sc[j]);
    }
    if (h < 15){ qf0 = qn0; qf1 = qn1; }
  }

  int qcol = qt*64 + w*16 + row_l;
  unsigned short* dst = invb + (size_t)b*4194304 + (size_t)qcol*2048 + kt*64 + kgrp*4;
  #pragma unroll
  for (int ks = 0; ks < 4; ks++){
    float r0 = 1.f/esum[ks][0], r1 = 1.f/esum[ks][1];
    float r2 = 1.f/esum[ks][2], r3 = 1.f/esum[ks][3];
    unsigned lo, hi;
    asm("v_cvt_pk_bf16_f32 %0, %1, %2" : "=v"(lo) : "v"(r0), "v"(r1));
    asm("v_cvt_pk_bf16_f32 %0, %1, %2" : "=v"(hi) : "v"(r2), "v"(r3));
    uint2 pk; pk.x = lo; pk.y = hi;
    *(uint2*)&dst[ks*16] = pk;
  }
}

// ---------------- PV-pass v9: uniform pair blocks, K ring-3 POST-barrier, 3 blocks/CU ----------------
// grid 512 = (b, h, pair i) XCD-swizzled; block runs q-tile i (i+1 tiles) then 31-i (32-i tiles).
// ALL staging post-barrier: stageK(kt+2) into (kt+2)%3 overwrites K(kt-1)'s buffer — safe, every
// wave passed barrier(kt) only after finishing compute(kt-1) (same proof as V ring-2, R12-proven).
// LDS = 24 + 16 + 9.25 = 49.25 KB -> 3 blocks/CU. FIFO (ops newer than stageV(kt)):
// first iter nx1?10:4 (qf,K0,V0,inv0,K1 + inv1); steady nx1?4:0 (inv(kt+1) only).
__launch_bounds__(256)
__global__ void pv_kernel(const unsigned short* __restrict__ qbuf,
                          const unsigned short* __restrict__ kb,
                          const unsigned short* __restrict__ vt,
                          const unsigned short* __restrict__ invb,
                          const float* __restrict__ sufv,
                          unsigned short* __restrict__ ab)
{
  __shared__ unsigned short Kst[3][4096];   // 24 KB
  __shared__ unsigned short Vst[2][4096];   // 16 KB
  __shared__ unsigned short Wsh[4][1152];   // 9.25 KB (per-wave private)

  int bid = blockIdx.x;                      // 512 = 8 * 64
  int blk = ((bid & 7) << 6) | (bid >> 3);   // XCD swizzle (bijective)
  int i = blk & 15;
  int h = (blk >> 4) & 15;
  int b = blk >> 8;

  int tid = threadIdx.x, lane = tid & 63, w = tid >> 6;
  int row_l = lane & 15, kgrp = lane >> 4;

  const unsigned short* KT = kb + (size_t)((b*16 + h)*32) * 4096;
  const unsigned short* VT = vt + (size_t)((b*16 + h)*32) * 4096;
  int sgoff = (w*128 + lane)*8;
  unsigned short* Wsw = &Wsh[w][0];

  int eK[4];
  #pragma unroll
  for (int ks = 0; ks < 4; ks++){
    int row = ks*16 + row_l;
    eK[ks] = (row*64 + kgrp*8) ^ ((row & 7) << 3);
  }

  auto stageK = [&](int kt, int buf){
    gll16(KT + (size_t)kt*4096 + sgoff,       (void*)(&Kst[buf][0] + w*1024));
    gll16(KT + (size_t)kt*4096 + sgoff + 512, (void*)(&Kst[buf][0] + w*1024 + 512));
  };
  auto stageV = [&](int kt, int buf){
    gll16(VT + (size_t)kt*4096 + sgoff,       (void*)(&Vst[buf][0] + w*1024));
    gll16(VT + (size_t)kt*4096 + sgoff + 512, (void*)(&Vst[buf][0] + w*1024 + 512));
  };

  auto run = [&](int qt, int k1t){            // k-range [0, k1t)
    int q0 = qt * 64;
    int qv = q0 + w*16 + row_l;
    const unsigned short* qrow_p = qbuf + (size_t)(b*2048 + qv) * 1024 + h*64;
    s16x8 qf0 = *(const s16x8*)&qrow_p[kgrp*8];
    s16x8 qf1 = *(const s16x8*)&qrow_p[32 + kgrp*8];
    SB();                                     // pin qf loads before the counted region
    const unsigned short* ivrow = invb + (size_t)b*4194304 + (size_t)qv*2048 + kgrp*4;

    f32x4 pvv[4];
    #pragma unroll
    for (int d = 0; d < 4; d++) pvv[d] = (f32x4){0.f,0.f,0.f,0.f};

    __syncthreads();                          // all waves done with previous segment's buffers
    // prologue: K(0)[2], V(0)[2], inv(0)[4], K(1)[2]
    stageK(0, 0);
    stageV(0, 0);
    s16x4 i1[4];
    #pragma unroll
    for (int ks = 0; ks < 4; ks++) i1[ks] = *(const s16x4*)&ivrow[ks*16];
    if (1 < k1t) stageK(1, 1);
    SB();

    for (int kt = 0; kt < k1t; kt++){
      bool nx1 = (kt + 1 < k1t), nx2 = (kt + 2 < k1t);
      bool first = (kt == 0);

      s16x4 icur[4];
      #pragma unroll
      for (int ks = 0; ks < 4; ks++) icur[ks] = i1[ks];
      if (nx1){
        #pragma unroll
        for (int ks = 0; ks < 4; ks++) i1[ks] = *(const s16x4*)&ivrow[(kt+1)*64 + ks*16];  // 4 vm
      }
      SB();
      // wait: stageK(kt) and stageV(kt) retired (audited newer-op counts)
      if (first){
        if (nx1) VMCNT(10);
        else     VMCNT(4);
      } else {
        if (nx1) VMCNT(4);
        else     VMCNT(0);
      }
      SB();
      __builtin_amdgcn_s_barrier();           // publish K(kt), V(kt); all compute(kt-1) done
      SB();
      if (nx2) stageK(kt+2, (kt+2) % 3);      // POST-barrier: K(kt-1) buffer overwrite safe
      if (nx1) stageV(kt+1, (kt+1) & 1);      // POST-barrier: V(kt-1) buffer overwrite safe
      SB();

      const unsigned short* kl = &Kst[kt % 3][0];
      const unsigned short* vl = &Vst[kt & 1][0];
      // QK^T (swapped: rows=key, cols=q); Q pre-scaled by log2e
      f32x4 sc[4];
      #pragma unroll
      for (int ks = 0; ks < 4; ks++){
        s16x8 a0 = *(const s16x8*)&kl[eK[ks]];
        s16x8 a1 = *(const s16x8*)&kl[eK[ks] ^ 32];
        sc[ks] = __builtin_amdgcn_mfma_f32_16x16x32_bf16(a0, qf0, (f32x4){0.f,0.f,0.f,0.f}, 0, 0, 0);
        sc[ks] = __builtin_amdgcn_mfma_f32_16x16x32_bf16(a1, qf1, sc[ks], 0, 0, 0);
      }

      // weights: w = exp2(s') * invD (masked -> exactly 1/16, diagonal tile only)
      if (kt == qt){
        int kbase = kt*64 + kgrp*4;
        #pragma unroll
        for (int ks = 0; ks < 4; ks++){
          #pragma unroll
          for (int j = 0; j < 4; j++){
            float wv = exp2i(sc[ks][j]) * bf2f((unsigned short)icur[ks][j]);
            sc[ks][j] = (kbase + ks*16 + j > qv) ? 0.0625f : wv;
          }
          unsigned lo, hi;
          asm("v_cvt_pk_bf16_f32 %0, %1, %2" : "=v"(lo) : "v"(sc[ks][0]), "v"(sc[ks][1]));
          asm("v_cvt_pk_bf16_f32 %0, %1, %2" : "=v"(hi) : "v"(sc[ks][2]), "v"(sc[ks][3]));
          uint2 pk2; pk2.x = lo; pk2.y = hi;
          *(uint2*)&Wsw[row_l*72 + ks*16 + kgrp*4] = pk2;
        }
      } else {
        #pragma unroll
        for (int ks = 0; ks < 4; ks++){
          #pragma unroll
          for (int j = 0; j < 4; j++)
            sc[ks][j] = exp2i(sc[ks][j]) * bf2f((unsigned short)icur[ks][j]);
          unsigned lo, hi;
          asm("v_cvt_pk_bf16_f32 %0, %1, %2" : "=v"(lo) : "v"(sc[ks][0]), "v"(sc[ks][1]));
          asm("v_cvt_pk_bf16_f32 %0, %1, %2" : "=v"(hi) : "v"(sc[ks][2]), "v"(sc[ks][3]));
          uint2 pk2; pk2.x = lo; pk2.y = hi;
          *(uint2*)&Wsw[row_l*72 + ks*16 + kgrp*4] = pk2;
        }
      }

      // PV (per-wave private Ws: same-wave lgkm ordering, no barrier)
      #pragma unroll
      for (int kc = 0; kc < 2; kc++){
        s16x8 af = *(const s16x8*)&Wsw[row_l*72 + kc*32 + kgrp*8];
        #pragma unroll
        for (int dq = 0; dq < 4; dq++){
          s16x8 vf = *(const s16x8*)&vl[eK[dq] ^ (kc*32)];
          pvv[dq] = __builtin_amdgcn_mfma_f32_16x16x32_bf16(af, vf, pvv[dq], 0, 0, 0);
        }
      }
    }

    // epilogue (direct): rows q = q0 + w*16 + kgrp*4 + j; cols d = dq*16 + row_l
    int tsuf = qt + 1;
    #pragma unroll
    for (int dq = 0; dq < 4; dq++){
      int d = dq*16 + row_l;
      float suf = sufv[((size_t)(b*16 + h)*33 + tsuf)*64 + d];
      #pragma unroll
      for (int j = 0; j < 4; j++){
        int qo = q0 + w*16 + kgrp*4 + j;
        ab[(size_t)(b*2048 + qo)*1024 + h*64 + d] = f2bf(pvv[dq][j] + 0.0625f * suf);
      }
    }
  };

  run(i, i + 1);
  run(31 - i, 32 - i);
}

// ---------------- host ----------------
extern "C" void kernel_launch(void* const* d_in, const int* in_sizes, int n_in,
                              void* d_out, int out_size, void* d_ws, size_t ws_size,
                              hipStream_t stream) {
  (void)in_sizes; (void)n_in; (void)out_size; (void)ws_size;
  const float* x  = (const float*)d_in[0];
  const float* Wa = (const float*)d_in[1];
  const float* ba = (const float*)d_in[2];
  const float* Wp = (const float*)d_in[3];
  const float* bp = (const float*)d_in[4];
  float* out = (float*)d_out;

  char* ws = (char*)d_ws;
  size_t off = 0;
  auto alloc = [&](size_t bytes) -> void* {
    void* p = ws + off;
    off += (bytes + 255) & ~(size_t)255;
    return p;
  };
  unsigned short* xb   = (unsigned short*)alloc((size_t)4096*1024*2);
  unsigned short* WaT  = (unsigned short*)alloc((size_t)3072*1024*2);
  unsigned short* WpT  = (unsigned short*)alloc((size_t)1024*1024*2);
  unsigned short* qbuf = (unsigned short*)alloc((size_t)4096*1024*2);
  unsigned short* ktile= (unsigned short*)alloc((size_t)4096*1024*2);
  unsigned short* vtile= (unsigned short*)alloc((size_t)4096*1024*2);
  unsigned short* abuf = (unsigned short*)alloc((size_t)4096*1024*2);
  unsigned short* invb = (unsigned short*)alloc((size_t)2*2048*2048*2); // bf16 invD
  float* sufv          = (float*)alloc((size_t)32*33*64*4);

  // 1) conversions
  cvt_kernel<<<2048, 256, 0, stream>>>(x, xb, 4096*1024/8);
  transpose_cvt<<<dim3(3072/32, 1024/32), dim3(32, 8), 0, stream>>>(Wa, WaT, 1024, 3072);
  transpose_cvt<<<dim3(1024/32, 1024/32), dim3(32, 8), 0, stream>>>(Wp, WpT, 1024, 1024);

  // 2) QKV GEMM -> qbuf / ktile / vtile (V via LDS-transposed coalesced stores)
  gemm_kernel<0,128><<<dim3(24, 32), 256, 0, stream>>>(xb, WaT, ba, 3072, qbuf, ktile, vtile, nullptr);

  // 3) V suffix sums
  sufv_kernel<<<32, 256, 0, stream>>>(vtile, sufv);

  // 4) denominator pass (bf16 invD)
  dpass_kernel<<<1056, 256, 0, stream>>>(qbuf, ktile, invb);

  // 5) PV pass (uniform pair blocks, ring-3 post-barrier, 3 blocks/CU)
  pv_kernel<<<512, 256, 0, stream>>>(qbuf, ktile, vtile, invb, sufv, abuf);

  // 6) projection GEMM (BM=64 -> 512 blocks, 2/CU)
  gemm_kernel<1,64><<<dim3(1024/128, 4096/64), 256, 0, stream>>>(abuf, WpT, bp, 1024, nullptr, nullptr, nullptr, out);
}

// Round 15
// 154.439 us; speedup vs baseline: 1.4084x; 1.0246x over previous
//
#include <hip/hip_runtime.h>

#define DI __device__ __forceinline__

typedef __attribute__((ext_vector_type(8))) short s16x8;
typedef __attribute__((ext_vector_type(4))) short s16x4;
typedef __attribute__((ext_vector_type(4))) float f32x4;

DI unsigned short f2bf(float f){
  unsigned u = __float_as_uint(f);
  u = (u + 0x7FFFu + ((u >> 16) & 1u)) >> 16;
  return (unsigned short)u;
}
DI float bf2f(unsigned short h){
  return __uint_as_float(((unsigned)h) << 16);
}
DI float exp2i(float x){ float r; asm("v_exp_f32 %0, %1" : "=v"(r) : "v"(x)); return r; }

DI void gll16(const void* g, void* l){
  __builtin_amdgcn_global_load_lds((const __attribute__((address_space(1))) void*)g,
                                   (__attribute__((address_space(3))) void*)l, 16, 0, 0);
}

#define VMCNT(n) asm volatile("s_waitcnt vmcnt(" #n ")" ::: "memory")
#define SB() __builtin_amdgcn_sched_barrier(0)

// ---------------- merged prep: x fp32->bf16, Wa^T, Wp^T ----------------
// blocks 0..2047: cvt (i = blk*256+tid, 8 floats each)
// blocks 2048..5119: transpose Wa (1024x3072 -> 3072x1024), k = blk-2048: bx=k%96, by=k/96
// blocks 5120..6143: transpose Wp (1024x1024), k = blk-5120: bx=k%32, by=k/32
__global__ void prep_kernel(const float* __restrict__ x, unsigned short* __restrict__ xb,
                            const float* __restrict__ Wa, unsigned short* __restrict__ WaT,
                            const float* __restrict__ Wp, unsigned short* __restrict__ WpT)
{
  __shared__ float t[32][33];
  int blk = blockIdx.x, tid = threadIdx.x;
  if (blk < 2048){
    int i = blk * 256 + tid;
    const float4* p = (const float4*)x + (size_t)i * 2;
    float4 a = p[0], b = p[1];
    s16x8 o;
    o[0] = (short)f2bf(a.x); o[1] = (short)f2bf(a.y); o[2] = (short)f2bf(a.z); o[3] = (short)f2bf(a.w);
    o[4] = (short)f2bf(b.x); o[5] = (short)f2bf(b.y); o[6] = (short)f2bf(b.z); o[7] = (short)f2bf(b.w);
    ((s16x8*)xb)[i] = o;
  } else {
    const float* in; unsigned short* out; int R, C, bx, by;
    if (blk < 5120){
      int k = blk - 2048; in = Wa; out = WaT; R = 1024; C = 3072; bx = k % 96; by = k / 96;
    } else {
      int k = blk - 5120; in = Wp; out = WpT; R = 1024; C = 1024; bx = k % 32; by = k / 32;
    }
    int c0 = bx * 32, r0 = by * 32;
    int tx = tid & 31, ty = tid >> 5;  // 32 x 8
    #pragma unroll
    for (int i = 0; i < 4; i++)
      t[ty + i*8][tx] = in[(size_t)(r0 + ty + i*8) * C + c0 + tx];
    __syncthreads();
    #pragma unroll
    for (int i = 0; i < 4; i++)
      out[(size_t)(c0 + ty + i*8) * R + r0 + tx] = f2bf(t[tx][ty + i*8]);
  }
}

// ---------------- GEMM (m97 structure): C[M x N] = A[M x K] * Wt[N x K]^T + bias ----------------
// MODE 0 (BM=128): qkv -> qbuf rows (Q pre-scaled by log2e), ktile swz (direct),
//                  vtile swz via LDS-transposed coalesced stores.
// MODE 1 (BM=64): proj -> fp32 out.
// Both: XCD-contiguous block swizzle (nwg % 8 == 0).
template<int MODE, int BM>
__launch_bounds__(256)
__global__ void gemm_kernel(const unsigned short* __restrict__ A,
                            const unsigned short* __restrict__ Wt,
                            const float* __restrict__ bias,
                            int N,
                            unsigned short* __restrict__ qb,
                            unsigned short* __restrict__ kb,
                            unsigned short* __restrict__ vt,
                            float* __restrict__ out)
{
  constexpr int MI = BM / 32;
  constexpr int AC = BM / 32;
  const int K = 1024;
  __shared__ __align__(16) unsigned short Sm[BM*64 + 128*64];
  unsigned short* As = Sm;
  unsigned short* Bs = Sm + BM*64;

  int lin = blockIdx.y * gridDim.x + blockIdx.x;
  int chunk = (gridDim.x * gridDim.y) >> 3;
  int v = (lin & 7) * chunk + (lin >> 3);
  int bx = v % gridDim.x, by = v / gridDim.x;
  int m0 = by * BM, n0 = bx * 128;

  int tid = threadIdx.x;
  int lane = tid & 63, w = tid >> 6;
  int row_l = lane & 15, kgrp = lane >> 4;
  int wm = (w >> 1) * (MI * 16), wn = (w & 1) * 64;

  const unsigned short* asrc[AC];
  const unsigned short* bsrc[4];
  int ldsoA[AC], ldsoB[4];
  int chnk = (lane & 7) ^ (lane >> 3);
  #pragma unroll
  for (int c4 = 0; c4 < AC; c4++){
    int r = c4*32 + w*8 + (lane >> 3);
    asrc[c4] = A + (size_t)(m0 + r) * K + chnk*8;
    ldsoA[c4] = (c4*32 + w*8) * 64;
  }
  #pragma unroll
  for (int c4 = 0; c4 < 4; c4++){
    int r = c4*32 + w*8 + (lane >> 3);
    bsrc[c4] = Wt + (size_t)(n0 + r) * K + chnk*8;
    ldsoB[c4] = (c4*32 + w*8) * 64;
  }
  int eA[MI], eB[4];
  #pragma unroll
  for (int i = 0; i < MI; i++){
    int ra = wm + i*16 + row_l;
    eA[i] = (ra*64 + kgrp*8) ^ ((ra & 7) << 3);
  }
  #pragma unroll
  for (int i = 0; i < 4; i++){
    int rb = wn + i*16 + row_l;
    eB[i] = (rb*64 + kgrp*8) ^ ((rb & 7) << 3);
  }

  f32x4 acc[MI][4];
  #pragma unroll
  for (int i = 0; i < MI; i++)
    #pragma unroll
    for (int j = 0; j < 4; j++)
      acc[i][j] = (f32x4){0.f, 0.f, 0.f, 0.f};

  for (int k0 = 0; k0 < K; k0 += 64){
    #pragma unroll
    for (int c4 = 0; c4 < AC; c4++)
      gll16(asrc[c4] + k0, (void*)(As + ldsoA[c4]));
    #pragma unroll
    for (int c4 = 0; c4 < 4; c4++)
      gll16(bsrc[c4] + k0, (void*)(Bs + ldsoB[c4]));
    __syncthreads();
    #pragma unroll
    for (int kc = 0; kc < 2; kc++){
      s16x8 af[MI], bfr[4];
      #pragma unroll
      for (int mi = 0; mi < MI; mi++)
        af[mi] = *(const s16x8*)&As[eA[mi] ^ (kc*32)];
      #pragma unroll
      for (int ni = 0; ni < 4; ni++)
        bfr[ni] = *(const s16x8*)&Bs[eB[ni] ^ (kc*32)];
      #pragma unroll
      for (int mi = 0; mi < MI; mi++)
        #pragma unroll
        for (int ni = 0; ni < 4; ni++)
          acc[mi][ni] = __builtin_amdgcn_mfma_f32_16x16x32_bf16(af[mi], bfr[ni], acc[mi][ni], 0, 0, 0);
    }
    __syncthreads();
  }

  if (MODE == 0){
    unsigned long long* ldsT = (unsigned long long*)Sm;   // [np 0..127][mq 0..31] u64
    #pragma unroll
    for (int mi = 0; mi < MI; mi++){
      #pragma unroll
      for (int ni = 0; ni < 4; ni++){
        int np = wn + ni*16 + row_l;
        int gc = n0 + np;
        int hh = gc / 192, cc = gc % 192;
        float bia = bias[gc];
        if (cc < 128){
          #pragma unroll
          for (int j = 0; j < 4; j++){
            int gr = m0 + wm + mi*16 + kgrp*4 + j;
            float v2 = acc[mi][ni][j] + bia;
            if (cc < 64){
              qb[(size_t)gr * 1024 + hh*64 + cc] = f2bf(v2 * 1.44269504f);
            } else {
              int d = cc - 64; int b = gr >> 11, s = gr & 2047;
              int kt = s >> 6, kk = s & 63;
              kb[(size_t)((b*16 + hh)*32 + kt) * 4096 + ((kk*64 + d) ^ ((kk & 7) << 3))] = f2bf(v2);
            }
          }
        } else {
          float v0 = acc[mi][ni][0] + bia, v1 = acc[mi][ni][1] + bia;
          float v2 = acc[mi][ni][2] + bia, v3 = acc[mi][ni][3] + bia;
          unsigned lo, hi;
          asm("v_cvt_pk_bf16_f32 %0, %1, %2" : "=v"(lo) : "v"(v0), "v"(v1));
          asm("v_cvt_pk_bf16_f32 %0, %1, %2" : "=v"(hi) : "v"(v2), "v"(v3));
          int mq = (wm + mi*16 + kgrp*4) >> 2;
          ldsT[np*32 + (mq ^ ((np & 7) << 2))] = ((unsigned long long)hi << 32) | (unsigned long long)lo;
        }
      }
    }
    __syncthreads();
    int bb = m0 >> 11, s_base = m0 & 2047;
    for (int item = tid; item < 2048; item += 256){
      int np = item >> 4;
      int gcv = n0 + np;
      int cc = gcv % 192;
      if (cc < 128) continue;
      int d = cc - 128, hh = gcv / 192;
      int sub = (item >> 3) & 1;
      int c = item & 7;
      int mq0 = sub*16 + c*2;
      s16x8 val = *(const s16x8*)&Sm[np*128 + ((mq0 ^ ((np & 7) << 2)) << 2)];
      size_t base = ((size_t)((bb*16 + hh)*32) + (s_base >> 6) + sub) * 4096 + d*64 + ((c ^ (d & 7)) << 3);
      *(s16x8*)&vt[base] = val;
    }
  } else {
    #pragma unroll
    for (int mi = 0; mi < MI; mi++){
      #pragma unroll
      for (int ni = 0; ni < 4; ni++){
        #pragma unroll
        for (int j = 0; j < 4; j++){
          int gr = m0 + wm + mi*16 + kgrp*4 + j;
          int gc = n0 + wn + ni*16 + row_l;
          out[(size_t)gr * N + gc] = acc[mi][ni][j] + bias[gc];
        }
      }
    }
  }
}

// ---------------- V suffix sums (64-key granularity): sufv[bh][t in 0..32][64d] ----------------
__global__ void sufv_kernel(const unsigned short* __restrict__ vt, float* __restrict__ sufv){
  __shared__ float tot[4][64];
  int bh = blockIdx.x;                 // 32
  int tid = threadIdx.x;               // 256
  int tq = tid >> 6, d = tid & 63;
  const unsigned short* base = vt + (size_t)bh * 32 * 4096;
  float s[8];
  float run = 0.f;
  for (int j = 7; j >= 0; j--){
    int t = tq*8 + j;
    float rs = 0.f;
    #pragma unroll
    for (int c = 0; c < 8; c++){
      int idx = (d*64 + c*8) ^ ((d & 7) << 3);
      s16x8 v = *(const s16x8*)&base[(size_t)t*4096 + idx];
      #pragma unroll
      for (int e = 0; e < 8; e++) rs += bf2f((unsigned short)v[e]);
    }
    run += rs; s[j] = run;
  }
  tot[tq][d] = run;
  __syncthreads();
  float carry = 0.f;
  for (int t2 = tq+1; t2 < 4; t2++) carry += tot[t2][d];
  #pragma unroll
  for (int j = 0; j < 8; j++)
    sufv[((size_t)bh*33 + tq*8 + j)*64 + d] = s[j] + carry;
  if (tid < 64) sufv[((size_t)bh*33 + 32)*64 + tid] = 0.f;
}

// ---------------- D-pass (R13-proven v1): invb[b][q][k] (bf16), single-head ring-4 lead-2 ----------------
__launch_bounds__(256)
__global__ void dpass_kernel(const unsigned short* __restrict__ qbuf,
                             const unsigned short* __restrict__ kb,
                             unsigned short* __restrict__ invb)
{
  __shared__ unsigned short Kst[4][4096];
  int bid = blockIdx.x;                       // 1056 = 8 * 132
  int blk = (bid & 7) * 132 + (bid >> 3);     // XCD swizzle (bijective)
  int b = blk / 528, t = blk % 528;
  int kt = (int)(32.5f - sqrtf(1056.25f - 2.f*t));
  while (kt*(65-kt)/2 > t) kt--;
  while ((kt+1)*(64-kt)/2 <= t) kt++;
  int qt = kt + (t - kt*(65-kt)/2);

  int tid = threadIdx.x, lane = tid & 63, w = tid >> 6;
  int row_l = lane & 15, kgrp = lane >> 4;

  const unsigned short* ktb = kb + ((size_t)(b*16)*32 + kt) * 4096;
  int sgoff = (w*128 + lane)*8;

  auto stage = [&](int hh, int buf){
    const unsigned short* src = ktb + (size_t)hh * 131072;
    gll16(src + sgoff,       (void*)(&Kst[buf][0] + w*1024));
    gll16(src + sgoff + 512, (void*)(&Kst[buf][0] + w*1024 + 512));
  };

  int e0[4];
  #pragma unroll
  for (int ks = 0; ks < 4; ks++){
    int row = ks*16 + row_l;
    e0[ks] = (row*64 + kgrp*8) ^ ((row & 7) << 3);
  }

  stage(0, 0);
  stage(1, 1);

  f32x4 esum[4];
  #pragma unroll
  for (int ks = 0; ks < 4; ks++) esum[ks] = (f32x4){0.f,0.f,0.f,0.f};

  const unsigned short* qrow_p = qbuf + (size_t)(b*2048 + qt*64 + w*16 + row_l) * 1024;
  s16x8 qf0 = *(const s16x8*)&qrow_p[kgrp*8];
  s16x8 qf1 = *(const s16x8*)&qrow_p[32 + kgrp*8];

  for (int h = 0; h < 16; h++){
    s16x8 qn0, qn1;
    if (h < 15){
      qn0 = *(const s16x8*)&qrow_p[(h+1)*64 + kgrp*8];
      qn1 = *(const s16x8*)&qrow_p[(h+1)*64 + 32 + kgrp*8];
    }
    if (h + 2 < 16) stage(h+2, (h+2) & 3);
    SB();
    if (h < 14)      VMCNT(8);
    else if (h < 15) VMCNT(6);
    else             VMCNT(2);
    SB();
    __builtin_amdgcn_s_barrier();
    SB();

    const unsigned short* kl = &Kst[h & 3][0];
    #pragma unroll
    for (int ks = 0; ks < 4; ks++){
      s16x8 a0 = *(const s16x8*)&kl[e0[ks]];
      s16x8 a1 = *(const s16x8*)&kl[e0[ks] ^ 32];
      f32x4 sc = __builtin_amdgcn_mfma_f32_16x16x32_bf16(a0, qf0, (f32x4){0.f,0.f,0.f,0.f}, 0, 0, 0);
      sc = __builtin_amdgcn_mfma_f32_16x16x32_bf16(a1, qf1, sc, 0, 0, 0);
      #pragma unroll
      for (int j = 0; j < 4; j++) esum[ks][j] += exp2i(sc[j]);
    }
    if (h < 15){ qf0 = qn0; qf1 = qn1; }
  }

  int qcol = qt*64 + w*16 + row_l;
  unsigned short* dst = invb + (size_t)b*4194304 + (size_t)qcol*2048 + kt*64 + kgrp*4;
  #pragma unroll
  for (int ks = 0; ks < 4; ks++){
    float r0 = 1.f/esum[ks][0], r1 = 1.f/esum[ks][1];
    float r2 = 1.f/esum[ks][2], r3 = 1.f/esum[ks][3];
    unsigned lo, hi;
    asm("v_cvt_pk_bf16_f32 %0, %1, %2" : "=v"(lo) : "v"(r0), "v"(r1));
    asm("v_cvt_pk_bf16_f32 %0, %1, %2" : "=v"(hi) : "v"(r2), "v"(r3));
    uint2 pk; pk.x = lo; pk.y = hi;
    *(uint2*)&dst[ks*16] = pk;
  }
}

// ---------------- PV-pass v9 (R13-proven): uniform pair blocks, K ring-3 POST-barrier ----------------
__launch_bounds__(256)
__global__ void pv_kernel(const unsigned short* __restrict__ qbuf,
                          const unsigned short* __restrict__ kb,
                          const unsigned short* __restrict__ vt,
                          const unsigned short* __restrict__ invb,
                          const float* __restrict__ sufv,
                          unsigned short* __restrict__ ab)
{
  __shared__ unsigned short Kst[3][4096];   // 24 KB
  __shared__ unsigned short Vst[2][4096];   // 16 KB
  __shared__ unsigned short Wsh[4][1152];   // 9.25 KB (per-wave private)

  int bid = blockIdx.x;                      // 512 = 8 * 64
  int blk = ((bid & 7) << 6) | (bid >> 3);   // XCD swizzle (bijective)
  int i = blk & 15;
  int h = (blk >> 4) & 15;
  int b = blk >> 8;

  int tid = threadIdx.x, lane = tid & 63, w = tid >> 6;
  int row_l = lane & 15, kgrp = lane >> 4;

  const unsigned short* KT = kb + (size_t)((b*16 + h)*32) * 4096;
  const unsigned short* VT = vt + (size_t)((b*16 + h)*32) * 4096;
  int sgoff = (w*128 + lane)*8;
  unsigned short* Wsw = &Wsh[w][0];

  int eK[4];
  #pragma unroll
  for (int ks = 0; ks < 4; ks++){
    int row = ks*16 + row_l;
    eK[ks] = (row*64 + kgrp*8) ^ ((row & 7) << 3);
  }

  auto stageK = [&](int kt, int buf){
    gll16(KT + (size_t)kt*4096 + sgoff,       (void*)(&Kst[buf][0] + w*1024));
    gll16(KT + (size_t)kt*4096 + sgoff + 512, (void*)(&Kst[buf][0] + w*1024 + 512));
  };
  auto stageV = [&](int kt, int buf){
    gll16(VT + (size_t)kt*4096 + sgoff,       (void*)(&Vst[buf][0] + w*1024));
    gll16(VT + (size_t)kt*4096 + sgoff + 512, (void*)(&Vst[buf][0] + w*1024 + 512));
  };

  auto run = [&](int qt, int k1t){            // k-range [0, k1t)
    int q0 = qt * 64;
    int qv = q0 + w*16 + row_l;
    const unsigned short* qrow_p = qbuf + (size_t)(b*2048 + qv) * 1024 + h*64;
    s16x8 qf0 = *(const s16x8*)&qrow_p[kgrp*8];
    s16x8 qf1 = *(const s16x8*)&qrow_p[32 + kgrp*8];
    SB();                                     // pin qf loads before the counted region
    const unsigned short* ivrow = invb + (size_t)b*4194304 + (size_t)qv*2048 + kgrp*4;

    f32x4 pvv[4];
    #pragma unroll
    for (int d = 0; d < 4; d++) pvv[d] = (f32x4){0.f,0.f,0.f,0.f};

    __syncthreads();                          // all waves done with previous segment's buffers
    stageK(0, 0);
    stageV(0, 0);
    s16x4 i1[4];
    #pragma unroll
    for (int ks = 0; ks < 4; ks++) i1[ks] = *(const s16x4*)&ivrow[ks*16];
    if (1 < k1t) stageK(1, 1);
    SB();

    for (int kt = 0; kt < k1t; kt++){
      bool nx1 = (kt + 1 < k1t), nx2 = (kt + 2 < k1t);
      bool first = (kt == 0);

      s16x4 icur[4];
      #pragma unroll
      for (int ks = 0; ks < 4; ks++) icur[ks] = i1[ks];
      if (nx1){
        #pragma unroll
        for (int ks = 0; ks < 4; ks++) i1[ks] = *(const s16x4*)&ivrow[(kt+1)*64 + ks*16];  // 4 vm
      }
      SB();
      if (first){
        if (nx1) VMCNT(10);
        else     VMCNT(4);
      } else {
        if (nx1) VMCNT(4);
        else     VMCNT(0);
      }
      SB();
      __builtin_amdgcn_s_barrier();           // publish K(kt), V(kt); all compute(kt-1) done
      SB();
      if (nx2) stageK(kt+2, (kt+2) % 3);      // POST-barrier: K(kt-1) buffer overwrite safe
      if (nx1) stageV(kt+1, (kt+1) & 1);      // POST-barrier: V(kt-1) buffer overwrite safe
      SB();

      const unsigned short* kl = &Kst[kt % 3][0];
      const unsigned short* vl = &Vst[kt & 1][0];
      f32x4 sc[4];
      #pragma unroll
      for (int ks = 0; ks < 4; ks++){
        s16x8 a0 = *(const s16x8*)&kl[eK[ks]];
        s16x8 a1 = *(const s16x8*)&kl[eK[ks] ^ 32];
        sc[ks] = __builtin_amdgcn_mfma_f32_16x16x32_bf16(a0, qf0, (f32x4){0.f,0.f,0.f,0.f}, 0, 0, 0);
        sc[ks] = __builtin_amdgcn_mfma_f32_16x16x32_bf16(a1, qf1, sc[ks], 0, 0, 0);
      }

      if (kt == qt){
        int kbase = kt*64 + kgrp*4;
        #pragma unroll
        for (int ks = 0; ks < 4; ks++){
          #pragma unroll
          for (int j = 0; j < 4; j++){
            float wv = exp2i(sc[ks][j]) * bf2f((unsigned short)icur[ks][j]);
            sc[ks][j] = (kbase + ks*16 + j > qv) ? 0.0625f : wv;
          }
          unsigned lo, hi;
          asm("v_cvt_pk_bf16_f32 %0, %1, %2" : "=v"(lo) : "v"(sc[ks][0]), "v"(sc[ks][1]));
          asm("v_cvt_pk_bf16_f32 %0, %1, %2" : "=v"(hi) : "v"(sc[ks][2]), "v"(sc[ks][3]));
          uint2 pk2; pk2.x = lo; pk2.y = hi;
          *(uint2*)&Wsw[row_l*72 + ks*16 + kgrp*4] = pk2;
        }
      } else {
        #pragma unroll
        for (int ks = 0; ks < 4; ks++){
          #pragma unroll
          for (int j = 0; j < 4; j++)
            sc[ks][j] = exp2i(sc[ks][j]) * bf2f((unsigned short)icur[ks][j]);
          unsigned lo, hi;
          asm("v_cvt_pk_bf16_f32 %0, %1, %2" : "=v"(lo) : "v"(sc[ks][0]), "v"(sc[ks][1]));
          asm("v_cvt_pk_bf16_f32 %0, %1, %2" : "=v"(hi) : "v"(sc[ks][2]), "v"(sc[ks][3]));
          uint2 pk2; pk2.x = lo; pk2.y = hi;
          *(uint2*)&Wsw[row_l*72 + ks*16 + kgrp*4] = pk2;
        }
      }

      #pragma unroll
      for (int kc = 0; kc < 2; kc++){
        s16x8 af = *(const s16x8*)&Wsw[row_l*72 + kc*32 + kgrp*8];
        #pragma unroll
        for (int dq = 0; dq < 4; dq++){
          s16x8 vf = *(const s16x8*)&vl[eK[dq] ^ (kc*32)];
          pvv[dq] = __builtin_amdgcn_mfma_f32_16x16x32_bf16(af, vf, pvv[dq], 0, 0, 0);
        }
      }
    }

    int tsuf = qt + 1;
    #pragma unroll
    for (int dq = 0; dq < 4; dq++){
      int d = dq*16 + row_l;
      float suf = sufv[((size_t)(b*16 + h)*33 + tsuf)*64 + d];
      #pragma unroll
      for (int j = 0; j < 4; j++){
        int qo = q0 + w*16 + kgrp*4 + j;
        ab[(size_t)(b*2048 + qo)*1024 + h*64 + d] = f2bf(pvv[dq][j] + 0.0625f * suf);
      }
    }
  };

  run(i, i + 1);
  run(31 - i, 32 - i);
}

// ---------------- host ----------------
extern "C" void kernel_launch(void* const* d_in, const int* in_sizes, int n_in,
                              void* d_out, int out_size, void* d_ws, size_t ws_size,
                              hipStream_t stream) {
  (void)in_sizes; (void)n_in; (void)out_size; (void)ws_size;
  const float* x  = (const float*)d_in[0];
  const float* Wa = (const float*)d_in[1];
  const float* ba = (const float*)d_in[2];
  const float* Wp = (const float*)d_in[3];
  const float* bp = (const float*)d_in[4];
  float* out = (float*)d_out;

  char* ws = (char*)d_ws;
  size_t off = 0;
  auto alloc = [&](size_t bytes) -> void* {
    void* p = ws + off;
    off += (bytes + 255) & ~(size_t)255;
    return p;
  };
  unsigned short* xb   = (unsigned short*)alloc((size_t)4096*1024*2);
  unsigned short* WaT  = (unsigned short*)alloc((size_t)3072*1024*2);
  unsigned short* WpT  = (unsigned short*)alloc((size_t)1024*1024*2);
  unsigned short* qbuf = (unsigned short*)alloc((size_t)4096*1024*2);
  unsigned short* ktile= (unsigned short*)alloc((size_t)4096*1024*2);
  unsigned short* vtile= (unsigned short*)alloc((size_t)4096*1024*2);
  unsigned short* abuf = (unsigned short*)alloc((size_t)4096*1024*2);
  unsigned short* invb = (unsigned short*)alloc((size_t)2*2048*2048*2); // bf16 invD
  float* sufv          = (float*)alloc((size_t)32*33*64*4);

  // 1) merged prep: x->bf16, Wa^T, Wp^T
  prep_kernel<<<6144, 256, 0, stream>>>(x, xb, Wa, WaT, Wp, WpT);

  // 2) QKV GEMM -> qbuf / ktile / vtile (V via LDS-transposed coalesced stores)
  gemm_kernel<0,128><<<dim3(24, 32), 256, 0, stream>>>(xb, WaT, ba, 3072, qbuf, ktile, vtile, nullptr);

  // 3) V suffix sums
  sufv_kernel<<<32, 256, 0, stream>>>(vtile, sufv);

  // 4) denominator pass (R13-proven single-head ring-4)
  dpass_kernel<<<1056, 256, 0, stream>>>(qbuf, ktile, invb);

  // 5) PV pass (uniform pair blocks, ring-3 post-barrier, 3 blocks/CU)
  pv_kernel<<<512, 256, 0, stream>>>(qbuf, ktile, vtile, invb, sufv, abuf);

  // 6) projection GEMM (BM=64 -> 512 blocks, 2/CU)
  gemm_kernel<1,64><<<dim3(1024/128, 4096/64), 256, 0, stream>>>(abuf, WpT, bp, 1024, nullptr, nullptr, nullptr, out);
}